// Round 1
// baseline (1429.071 us; speedup 1.0000x reference)
//
#include <hip/hip_runtime.h>
#include <hip/hip_bf16.h>

// ---------------- problem constants (fixed by setup_inputs) ----------------
constexpr int NB    = 64;      // batch
constexpr int LMAX  = 1024;    // max vision tokens
constexpr int DD    = 1024;    // feature dim
constexpr int HSAE  = 16384;   // SAE latent dim
constexpr int TT    = 512;     // text tokens
constexpr int KV    = 8;       // views per batch
constexpr int TOPK  = 32;
constexpr int NROW_V = NB * KV;   // 512
constexpr int NROW_T = NB;        // 64

// output offsets (floats), concatenated in reference return order
constexpr size_t OUT_RECON_V = 0;                                   // [512,1024]
constexpr size_t OUT_VVIEWS  = OUT_RECON_V + (size_t)NROW_V * DD;   // [512,1024]
constexpr size_t OUT_RECON_T = OUT_VVIEWS + (size_t)NROW_V * DD;    // [64,1024]
constexpr size_t OUT_TGLOBAL = OUT_RECON_T + (size_t)NROW_T * DD;   // [64,1024]
constexpr size_t OUT_LAT_V   = OUT_TGLOBAL + (size_t)NROW_T * DD;   // [512,16384]
constexpr size_t OUT_LAT_T   = OUT_LAT_V + (size_t)NROW_V * HSAE;   // [64,16384]

// workspace offsets (floats)
constexpr size_t WS_VN    = 0;                                   // x_n for views [512,1024]
constexpr size_t WS_TN    = WS_VN + (size_t)NROW_V * DD;         // x_n for text  [64,1024]
constexpr size_t WS_IDX_V = WS_TN + (size_t)NROW_T * DD;         // int [512,32]
constexpr size_t WS_VAL_V = WS_IDX_V + (size_t)NROW_V * TOPK;    // f32 [512,32]
constexpr size_t WS_IDX_T = WS_VAL_V + (size_t)NROW_V * TOPK;    // int [64,32]
constexpr size_t WS_VAL_T = WS_IDX_T + (size_t)NROW_T * TOPK;    // f32 [64,32]

// ---------------- 1. text global pooling ----------------
// grid (NB, 4), block 256. thread owns one d.
__global__ __launch_bounds__(256) void pool_t_kernel(const float* __restrict__ t_pad,
                                                     const float* __restrict__ t_mask,
                                                     float* __restrict__ out_tg) {
    const int b  = blockIdx.x;
    const int d  = blockIdx.y * 256 + threadIdx.x;
    const float* tp = t_pad + (size_t)b * TT * DD + d;
    const float* tm = t_mask + (size_t)b * TT;
    float acc = 0.f, msum = 0.f;
#pragma unroll 8
    for (int t = 0; t < TT; ++t) {
        float m = tm[t];
        acc  = fmaf(m, tp[(size_t)t * DD], acc);
        msum += m;
    }
    out_tg[(size_t)b * DD + d] = acc / (msum + 1e-6f);
}

// ---------------- 2. gaussian view pooling ----------------
// grid (NB, 4), block 256; thread owns one d; all 8 views accumulated together.
__global__ __launch_bounds__(256) void pool_v_kernel(const float* __restrict__ v_pad,
                                                     const float* __restrict__ centers,
                                                     const int* __restrict__ grid_thws,
                                                     float* __restrict__ out_views) {
    __shared__ float m_lds[LMAX][KV];    // 32 KB
    __shared__ float part[256][KV];      // 8 KB
    __shared__ float den_s[KV];
    const int b   = blockIdx.x;
    const int tid = threadIdx.x;
    const int H = grid_thws[1];
    const int W = grid_thws[2];
    int L = H * W; if (L > LMAX) L = LMAX;

    float cx[KV], cy[KV];
#pragma unroll
    for (int k = 0; k < KV; ++k) {
        cx[k] = centers[((size_t)b * KV + k) * 2 + 0];
        cy[k] = centers[((size_t)b * KV + k) * 2 + 1];
    }
    float psum[KV];
#pragma unroll
    for (int k = 0; k < KV; ++k) psum[k] = 0.f;

    for (int l = tid; l < LMAX; l += 256) {
        if (l < L) {
            int iy = l / W, ix = l - iy * W;
            float gx = (ix + 0.5f) / (float)W;
            float gy = (iy + 0.5f) / (float)H;
#pragma unroll
            for (int k = 0; k < KV; ++k) {
                float dx = cx[k] - gx, dy = cy[k] - gy;
                float m = expf(-10.f * (dx * dx + dy * dy));
                m_lds[l][k] = m;
                psum[k] += m;
            }
        } else {
#pragma unroll
            for (int k = 0; k < KV; ++k) m_lds[l][k] = 0.f;
        }
    }
#pragma unroll
    for (int k = 0; k < KV; ++k) part[tid][k] = psum[k];
    __syncthreads();
    if (tid < KV) {   // deterministic serial reduce per view
        float s = 0.f;
        for (int i = 0; i < 256; ++i) s += part[i][tid];
        den_s[tid] = s + 1e-6f;
    }
    __syncthreads();

    const int d = blockIdx.y * 256 + tid;
    const float* vp = v_pad + (size_t)b * LMAX * DD + d;
    float acc[KV];
#pragma unroll
    for (int k = 0; k < KV; ++k) acc[k] = 0.f;
#pragma unroll 4
    for (int l = 0; l < LMAX; ++l) {
        if (l < L) {
            float v = vp[(size_t)l * DD];
#pragma unroll
            for (int k = 0; k < KV; ++k) acc[k] = fmaf(m_lds[l][k], v, acc[k]);
        }
    }
#pragma unroll
    for (int k = 0; k < KV; ++k)
        out_views[((size_t)(b * KV + k)) * DD + d] = acc[k] / den_s[k];
}

// ---------------- 3. row l2-normalize (views + t_global -> ws) ----------------
__global__ __launch_bounds__(256) void norm_rows_kernel(const float* __restrict__ out_buf,
                                                        float* __restrict__ ws) {
    const int r   = blockIdx.x;
    const int tid = threadIdx.x;
    const float* src;
    float* dst;
    if (r < NROW_V) {
        src = out_buf + OUT_VVIEWS + (size_t)r * DD;
        dst = ws + WS_VN + (size_t)r * DD;
    } else {
        src = out_buf + OUT_TGLOBAL + (size_t)(r - NROW_V) * DD;
        dst = ws + WS_TN + (size_t)(r - NROW_V) * DD;
    }
    float4 x = *(const float4*)(src + tid * 4);
    float ss = x.x * x.x + x.y * x.y + x.z * x.z + x.w * x.w;
#pragma unroll
    for (int off = 32; off; off >>= 1) ss += __shfl_down(ss, off);
    __shared__ float wsum[4];
    if ((tid & 63) == 0) wsum[tid >> 6] = ss;
    __syncthreads();
    float tot = wsum[0] + wsum[1] + wsum[2] + wsum[3];
    float scale = 1.f / fmaxf(sqrtf(tot), 1e-12f);
    float4 y;
    y.x = x.x * scale; y.y = x.y * scale; y.z = x.z * scale; y.w = x.w * scale;
    *(float4*)(dst + tid * 4) = y;
}

// ---------------- 4. f32 GEMM -> acts (fused enc-row-norm) ----------------
// C[m,h] = acts( clip( (x_n[m,:] . enc[h,:]) / max(||enc[h,:]||,1e-12) ) )
constexpr int BM = 128, BN = 128, KT = 16;

__global__ __launch_bounds__(256) void gemm_acts_kernel(const float* __restrict__ A,   // [M, D] normalized
                                                        const float* __restrict__ Bm,  // [HSAE, D] raw enc
                                                        float* __restrict__ outActs,   // [M, HSAE]
                                                        int M) {
    __shared__ __align__(16) float As[KT][BM + 4];
    __shared__ __align__(16) float Bs[KT][BN + 4];
    __shared__ float bn_part[BN][2];
    __shared__ float binv[BN];

    const int tid  = threadIdx.x;
    const int h0   = blockIdx.x * BN;
    const int m0   = blockIdx.y * BM;
    const int srow = tid >> 1;             // 0..127
    const int scol = (tid & 1) * 8;        // 0 or 8
    const int tx   = tid & 15;             // m direction
    const int ty   = tid >> 4;             // h direction
    const bool aval = (m0 + srow) < M;
    const float* aptr = A  + (size_t)(m0 + srow) * DD + scol;
    const float* bptr = Bm + (size_t)(h0 + srow) * DD + scol;

    float acc[8][8];
#pragma unroll
    for (int i = 0; i < 8; ++i)
#pragma unroll
        for (int j = 0; j < 8; ++j) acc[i][j] = 0.f;
    float bn = 0.f;

    for (int kt = 0; kt < DD; kt += KT) {
        float4 a0, a1;
        if (aval) {
            a0 = *(const float4*)(aptr + kt);
            a1 = *(const float4*)(aptr + kt + 4);
        } else {
            a0 = make_float4(0.f, 0.f, 0.f, 0.f); a1 = a0;
        }
        const float4 b0 = *(const float4*)(bptr + kt);
        const float4 b1 = *(const float4*)(bptr + kt + 4);
        bn += b0.x * b0.x + b0.y * b0.y + b0.z * b0.z + b0.w * b0.w;
        bn += b1.x * b1.x + b1.y * b1.y + b1.z * b1.z + b1.w * b1.w;

        __syncthreads();
        As[scol + 0][srow] = a0.x; As[scol + 1][srow] = a0.y;
        As[scol + 2][srow] = a0.z; As[scol + 3][srow] = a0.w;
        As[scol + 4][srow] = a1.x; As[scol + 5][srow] = a1.y;
        As[scol + 6][srow] = a1.z; As[scol + 7][srow] = a1.w;
        Bs[scol + 0][srow] = b0.x; Bs[scol + 1][srow] = b0.y;
        Bs[scol + 2][srow] = b0.z; Bs[scol + 3][srow] = b0.w;
        Bs[scol + 4][srow] = b1.x; Bs[scol + 5][srow] = b1.y;
        Bs[scol + 6][srow] = b1.z; Bs[scol + 7][srow] = b1.w;
        __syncthreads();

#pragma unroll
        for (int kk = 0; kk < KT; ++kk) {
            const float4 av0 = *(const float4*)&As[kk][tx * 8];
            const float4 av1 = *(const float4*)&As[kk][tx * 8 + 4];
            const float4 bv0 = *(const float4*)&Bs[kk][ty * 8];
            const float4 bv1 = *(const float4*)&Bs[kk][ty * 8 + 4];
            const float ar[8] = {av0.x, av0.y, av0.z, av0.w, av1.x, av1.y, av1.z, av1.w};
            const float br[8] = {bv0.x, bv0.y, bv0.z, bv0.w, bv1.x, bv1.y, bv1.z, bv1.w};
#pragma unroll
            for (int i = 0; i < 8; ++i)
#pragma unroll
                for (int j = 0; j < 8; ++j)
                    acc[i][j] = fmaf(ar[i], br[j], acc[i][j]);
        }
    }

    bn_part[srow][tid & 1] = bn;
    __syncthreads();
    if (tid < BN) {
        float s = bn_part[tid][0] + bn_part[tid][1];
        binv[tid] = 1.f / fmaxf(sqrtf(s), 1e-12f);
    }
    __syncthreads();

#pragma unroll
    for (int i = 0; i < 8; ++i) {
        const int m = m0 + tx * 8 + i;
        if (m < M) {
            float res[8];
#pragma unroll
            for (int j = 0; j < 8; ++j) {
                float c = acc[i][j] * binv[ty * 8 + j];
                c = fminf(1.f, fmaxf(-1.f, c));
                res[j] = 2.f - sqrtf(fmaxf(0.f, 2.f - 2.f * c));
            }
            float* op = outActs + (size_t)m * HSAE + h0 + ty * 8;
            *(float4*)op       = make_float4(res[0], res[1], res[2], res[3]);
            *(float4*)(op + 4) = make_float4(res[4], res[5], res[6], res[7]);
        }
    }
}

// ---------------- 5. top-32 per row + sparsify latent in place ----------------
// Matches jax.lax.top_k tie-breaking (equal values -> lower index first).
__global__ __launch_bounds__(256) void topk_kernel(float* __restrict__ out_buf,
                                                   float* __restrict__ ws) {
    const int r   = blockIdx.x;
    const int tid = threadIdx.x;
    float* row;
    int* idxp; float* valp;
    if (r < NROW_V) {
        row  = out_buf + OUT_LAT_V + (size_t)r * HSAE;
        idxp = (int*)(ws + WS_IDX_V) + (size_t)r * TOPK;
        valp = ws + WS_VAL_V + (size_t)r * TOPK;
    } else {
        const int rr = r - NROW_V;
        row  = out_buf + OUT_LAT_T + (size_t)rr * HSAE;
        idxp = (int*)(ws + WS_IDX_T) + (size_t)rr * TOPK;
        valp = ws + WS_VAL_T + (size_t)rr * TOPK;
    }

    __shared__ float vals[HSAE];       // 64 KB
    __shared__ float wv[4];
    __shared__ int   wi[4];
    __shared__ float lastV;
    __shared__ int   lastI;
    __shared__ float selV[TOPK];
    __shared__ int   selI[TOPK];

    for (int e = 0; e < HSAE / 256; ++e)
        vals[e * 256 + tid] = row[e * 256 + tid];
    if (tid == 0) { lastV = 1e30f; lastI = -1; }
    __syncthreads();

    for (int round = 0; round < TOPK; ++round) {
        const float lV = lastV;
        const int   lI = lastI;
        float bV = -1e30f;
        int   bI = 0x7fffffff;
        for (int e = 0; e < HSAE / 256; ++e) {
            const int i  = e * 256 + tid;
            const float v = vals[i];
            const bool elig   = (v < lV) || (v == lV && i > lI);
            const bool better = elig && (v > bV || (v == bV && i < bI));
            if (better) { bV = v; bI = i; }
        }
#pragma unroll
        for (int off = 32; off; off >>= 1) {
            const float ov = __shfl_down(bV, off);
            const int   oi = __shfl_down(bI, off);
            if (ov > bV || (ov == bV && oi < bI)) { bV = ov; bI = oi; }
        }
        if ((tid & 63) == 0) { wv[tid >> 6] = bV; wi[tid >> 6] = bI; }
        __syncthreads();
        if (tid == 0) {
            float fv = wv[0]; int fi = wi[0];
#pragma unroll
            for (int w = 1; w < 4; ++w)
                if (wv[w] > fv || (wv[w] == fv && wi[w] < fi)) { fv = wv[w]; fi = wi[w]; }
            selV[round] = fv; selI[round] = fi;
            lastV = fv; lastI = fi;
        }
        __syncthreads();
    }

    if (tid < TOPK) { idxp[tid] = selI[tid]; valp[tid] = selV[tid]; }
    // zero whole row, then scatter the 32 kept values
    for (int e = 0; e < HSAE / (256 * 4); ++e)
        *(float4*)(row + (size_t)(e * 256 + tid) * 4) = make_float4(0.f, 0.f, 0.f, 0.f);
    __syncthreads();
    if (tid < TOPK) row[selI[tid]] = selV[tid];
}

// ---------------- 6. sparse reconstruction ----------------
// block = one d; stage dec_w[d,:] (64KB) in LDS; gather 32 terms per row.
__global__ __launch_bounds__(256) void recon_kernel(const float* __restrict__ decw,  // [D, HSAE]
                                                    const float* __restrict__ decb,  // [D]
                                                    const int* __restrict__ idxp,    // [M, 32]
                                                    const float* __restrict__ valp,  // [M, 32]
                                                    float* __restrict__ outp,        // [M, D]
                                                    int M) {
    __shared__ float wrow[HSAE];  // 64 KB
    const int d   = blockIdx.x;
    const int tid = threadIdx.x;
    const float* wr = decw + (size_t)d * HSAE;
    for (int e = 0; e < HSAE / (256 * 4); ++e)
        *(float4*)&wrow[(size_t)(e * 256 + tid) * 4] = *(const float4*)(wr + (size_t)(e * 256 + tid) * 4);
    __syncthreads();
    const float bias = decb[d];
    for (int n = tid; n < M; n += 256) {
        float acc = bias;
#pragma unroll
        for (int k = 0; k < TOPK; ++k)
            acc = fmaf(valp[n * TOPK + k], wrow[idxp[n * TOPK + k]], acc);
        outp[(size_t)n * DD + d] = acc;
    }
}

// ---------------- launch ----------------
extern "C" void kernel_launch(void* const* d_in, const int* in_sizes, int n_in,
                              void* d_out, int out_size, void* d_ws, size_t ws_size,
                              hipStream_t stream) {
    const float* v_pad    = (const float*)d_in[0];
    // d_in[1] v_len: unused by the reference
    const int*   grid_thws = (const int*)d_in[2];
    const float* t_pad    = (const float*)d_in[3];
    const float* t_mask   = (const float*)d_in[4];
    const float* centers  = (const float*)d_in[5];
    const float* enc_v    = (const float*)d_in[6];
    const float* dec_v_w  = (const float*)d_in[7];
    const float* dec_v_b  = (const float*)d_in[8];
    const float* enc_t    = (const float*)d_in[9];
    const float* dec_t_w  = (const float*)d_in[10];
    const float* dec_t_b  = (const float*)d_in[11];
    float* out = (float*)d_out;
    float* ws  = (float*)d_ws;

    pool_t_kernel<<<dim3(NB, 4), 256, 0, stream>>>(t_pad, t_mask, out + OUT_TGLOBAL);
    pool_v_kernel<<<dim3(NB, 4), 256, 0, stream>>>(v_pad, centers, grid_thws, out + OUT_VVIEWS);
    norm_rows_kernel<<<NROW_V + NROW_T, 256, 0, stream>>>(out, ws);
    gemm_acts_kernel<<<dim3(HSAE / BN, NROW_V / BM), 256, 0, stream>>>(ws + WS_VN, enc_v, out + OUT_LAT_V, NROW_V);
    gemm_acts_kernel<<<dim3(HSAE / BN, 1), 256, 0, stream>>>(ws + WS_TN, enc_t, out + OUT_LAT_T, NROW_T);
    topk_kernel<<<NROW_V + NROW_T, 256, 0, stream>>>(out, ws);
    recon_kernel<<<DD, 256, 0, stream>>>(dec_v_w, dec_v_b, (const int*)(ws + WS_IDX_V), ws + WS_VAL_V,
                                         out + OUT_RECON_V, NROW_V);
    recon_kernel<<<DD, 256, 0, stream>>>(dec_t_w, dec_t_b, (const int*)(ws + WS_IDX_T), ws + WS_VAL_T,
                                         out + OUT_RECON_T, NROW_T);
}

// Round 2
// 1025.416 us; speedup vs baseline: 1.3937x; 1.3937x over previous
//
#include <hip/hip_runtime.h>
#include <hip/hip_bf16.h>

// ---------------- problem constants (fixed by setup_inputs) ----------------
constexpr int NB    = 64;      // batch
constexpr int LMAX  = 1024;    // max vision tokens
constexpr int DD    = 1024;    // feature dim
constexpr int HSAE  = 16384;   // SAE latent dim
constexpr int TT    = 512;     // text tokens
constexpr int KV    = 8;       // views per batch
constexpr int TOPK  = 32;
constexpr int NROW_V = NB * KV;   // 512
constexpr int NROW_T = NB;        // 64

// output offsets (floats), concatenated in reference return order
constexpr size_t OUT_RECON_V = 0;                                   // [512,1024]
constexpr size_t OUT_VVIEWS  = OUT_RECON_V + (size_t)NROW_V * DD;   // [512,1024]
constexpr size_t OUT_RECON_T = OUT_VVIEWS + (size_t)NROW_V * DD;    // [64,1024]
constexpr size_t OUT_TGLOBAL = OUT_RECON_T + (size_t)NROW_T * DD;   // [64,1024]
constexpr size_t OUT_LAT_V   = OUT_TGLOBAL + (size_t)NROW_T * DD;   // [512,16384]
constexpr size_t OUT_LAT_T   = OUT_LAT_V + (size_t)NROW_V * HSAE;   // [64,16384]

// workspace offsets (floats)
constexpr size_t WS_VN    = 0;                                   // x_n for views [512,1024]
constexpr size_t WS_TN    = WS_VN + (size_t)NROW_V * DD;         // x_n for text  [64,1024]
constexpr size_t WS_IDX_V = WS_TN + (size_t)NROW_T * DD;         // int [512,32]
constexpr size_t WS_VAL_V = WS_IDX_V + (size_t)NROW_V * TOPK;    // f32 [512,32]
constexpr size_t WS_IDX_T = WS_VAL_V + (size_t)NROW_V * TOPK;    // int [64,32]
constexpr size_t WS_VAL_T = WS_IDX_T + (size_t)NROW_T * TOPK;    // f32 [64,32]

// ---------------- 1. text global pooling ----------------
__global__ __launch_bounds__(256) void pool_t_kernel(const float* __restrict__ t_pad,
                                                     const float* __restrict__ t_mask,
                                                     float* __restrict__ out_tg) {
    const int b  = blockIdx.x;
    const int d  = blockIdx.y * 256 + threadIdx.x;
    const float* tp = t_pad + (size_t)b * TT * DD + d;
    const float* tm = t_mask + (size_t)b * TT;
    float acc = 0.f, msum = 0.f;
#pragma unroll 8
    for (int t = 0; t < TT; ++t) {
        float m = tm[t];
        acc  = fmaf(m, tp[(size_t)t * DD], acc);
        msum += m;
    }
    out_tg[(size_t)b * DD + d] = acc / (msum + 1e-6f);
}

// ---------------- 2. gaussian view pooling ----------------
__global__ __launch_bounds__(256) void pool_v_kernel(const float* __restrict__ v_pad,
                                                     const float* __restrict__ centers,
                                                     const int* __restrict__ grid_thws,
                                                     float* __restrict__ out_views) {
    __shared__ float m_lds[LMAX][KV];    // 32 KB
    __shared__ float part[256][KV];      // 8 KB
    __shared__ float den_s[KV];
    const int b   = blockIdx.x;
    const int tid = threadIdx.x;
    const int H = grid_thws[1];
    const int W = grid_thws[2];
    int L = H * W; if (L > LMAX) L = LMAX;

    float cx[KV], cy[KV];
#pragma unroll
    for (int k = 0; k < KV; ++k) {
        cx[k] = centers[((size_t)b * KV + k) * 2 + 0];
        cy[k] = centers[((size_t)b * KV + k) * 2 + 1];
    }
    float psum[KV];
#pragma unroll
    for (int k = 0; k < KV; ++k) psum[k] = 0.f;

    for (int l = tid; l < LMAX; l += 256) {
        if (l < L) {
            int iy = l / W, ix = l - iy * W;
            float gx = (ix + 0.5f) / (float)W;
            float gy = (iy + 0.5f) / (float)H;
#pragma unroll
            for (int k = 0; k < KV; ++k) {
                float dx = cx[k] - gx, dy = cy[k] - gy;
                float m = expf(-10.f * (dx * dx + dy * dy));
                m_lds[l][k] = m;
                psum[k] += m;
            }
        } else {
#pragma unroll
            for (int k = 0; k < KV; ++k) m_lds[l][k] = 0.f;
        }
    }
#pragma unroll
    for (int k = 0; k < KV; ++k) part[tid][k] = psum[k];
    __syncthreads();
    if (tid < KV) {   // deterministic serial reduce per view
        float s = 0.f;
        for (int i = 0; i < 256; ++i) s += part[i][tid];
        den_s[tid] = s + 1e-6f;
    }
    __syncthreads();

    const int d = blockIdx.y * 256 + tid;
    const float* vp = v_pad + (size_t)b * LMAX * DD + d;
    float acc[KV];
#pragma unroll
    for (int k = 0; k < KV; ++k) acc[k] = 0.f;
#pragma unroll 4
    for (int l = 0; l < LMAX; ++l) {
        if (l < L) {
            float v = vp[(size_t)l * DD];
#pragma unroll
            for (int k = 0; k < KV; ++k) acc[k] = fmaf(m_lds[l][k], v, acc[k]);
        }
    }
#pragma unroll
    for (int k = 0; k < KV; ++k)
        out_views[((size_t)(b * KV + k)) * DD + d] = acc[k] / den_s[k];
}

// ---------------- 3. row l2-normalize (views + t_global -> ws) ----------------
__global__ __launch_bounds__(256) void norm_rows_kernel(const float* __restrict__ out_buf,
                                                        float* __restrict__ ws) {
    const int r   = blockIdx.x;
    const int tid = threadIdx.x;
    const float* src;
    float* dst;
    if (r < NROW_V) {
        src = out_buf + OUT_VVIEWS + (size_t)r * DD;
        dst = ws + WS_VN + (size_t)r * DD;
    } else {
        src = out_buf + OUT_TGLOBAL + (size_t)(r - NROW_V) * DD;
        dst = ws + WS_TN + (size_t)(r - NROW_V) * DD;
    }
    float4 x = *(const float4*)(src + tid * 4);
    float ss = x.x * x.x + x.y * x.y + x.z * x.z + x.w * x.w;
#pragma unroll
    for (int off = 32; off; off >>= 1) ss += __shfl_down(ss, off);
    __shared__ float wsum[4];
    if ((tid & 63) == 0) wsum[tid >> 6] = ss;
    __syncthreads();
    float tot = wsum[0] + wsum[1] + wsum[2] + wsum[3];
    float scale = 1.f / fmaxf(sqrtf(tot), 1e-12f);
    float4 y;
    y.x = x.x * scale; y.y = x.y * scale; y.z = x.z * scale; y.w = x.w * scale;
    *(float4*)(dst + tid * 4) = y;
}

// ---------------- 4. f32 GEMM -> acts (fused enc-row-norm) ----------------
constexpr int BM = 128, BN = 128, KT = 16;

__global__ __launch_bounds__(256) void gemm_acts_kernel(const float* __restrict__ A,   // [M, D] normalized
                                                        const float* __restrict__ Bm,  // [HSAE, D] raw enc
                                                        float* __restrict__ outActs,   // [M, HSAE]
                                                        int M) {
    __shared__ __align__(16) float As[KT][BM + 4];
    __shared__ __align__(16) float Bs[KT][BN + 4];
    __shared__ float bn_part[BN][2];
    __shared__ float binv[BN];

    const int tid  = threadIdx.x;
    const int h0   = blockIdx.x * BN;
    const int m0   = blockIdx.y * BM;
    const int srow = tid >> 1;             // 0..127
    const int scol = (tid & 1) * 8;        // 0 or 8
    const int tx   = tid & 15;             // m direction
    const int ty   = tid >> 4;             // h direction
    const bool aval = (m0 + srow) < M;
    const float* aptr = A  + (size_t)(m0 + srow) * DD + scol;
    const float* bptr = Bm + (size_t)(h0 + srow) * DD + scol;

    float acc[8][8];
#pragma unroll
    for (int i = 0; i < 8; ++i)
#pragma unroll
        for (int j = 0; j < 8; ++j) acc[i][j] = 0.f;
    float bn = 0.f;

    for (int kt = 0; kt < DD; kt += KT) {
        float4 a0, a1;
        if (aval) {
            a0 = *(const float4*)(aptr + kt);
            a1 = *(const float4*)(aptr + kt + 4);
        } else {
            a0 = make_float4(0.f, 0.f, 0.f, 0.f); a1 = a0;
        }
        const float4 b0 = *(const float4*)(bptr + kt);
        const float4 b1 = *(const float4*)(bptr + kt + 4);
        bn += b0.x * b0.x + b0.y * b0.y + b0.z * b0.z + b0.w * b0.w;
        bn += b1.x * b1.x + b1.y * b1.y + b1.z * b1.z + b1.w * b1.w;

        __syncthreads();
        As[scol + 0][srow] = a0.x; As[scol + 1][srow] = a0.y;
        As[scol + 2][srow] = a0.z; As[scol + 3][srow] = a0.w;
        As[scol + 4][srow] = a1.x; As[scol + 5][srow] = a1.y;
        As[scol + 6][srow] = a1.z; As[scol + 7][srow] = a1.w;
        Bs[scol + 0][srow] = b0.x; Bs[scol + 1][srow] = b0.y;
        Bs[scol + 2][srow] = b0.z; Bs[scol + 3][srow] = b0.w;
        Bs[scol + 4][srow] = b1.x; Bs[scol + 5][srow] = b1.y;
        Bs[scol + 6][srow] = b1.z; Bs[scol + 7][srow] = b1.w;
        __syncthreads();

#pragma unroll
        for (int kk = 0; kk < KT; ++kk) {
            const float4 av0 = *(const float4*)&As[kk][tx * 8];
            const float4 av1 = *(const float4*)&As[kk][tx * 8 + 4];
            const float4 bv0 = *(const float4*)&Bs[kk][ty * 8];
            const float4 bv1 = *(const float4*)&Bs[kk][ty * 8 + 4];
            const float ar[8] = {av0.x, av0.y, av0.z, av0.w, av1.x, av1.y, av1.z, av1.w};
            const float br[8] = {bv0.x, bv0.y, bv0.z, bv0.w, bv1.x, bv1.y, bv1.z, bv1.w};
#pragma unroll
            for (int i = 0; i < 8; ++i)
#pragma unroll
                for (int j = 0; j < 8; ++j)
                    acc[i][j] = fmaf(ar[i], br[j], acc[i][j]);
        }
    }

    bn_part[srow][tid & 1] = bn;
    __syncthreads();
    if (tid < BN) {
        float s = bn_part[tid][0] + bn_part[tid][1];
        binv[tid] = 1.f / fmaxf(sqrtf(s), 1e-12f);
    }
    __syncthreads();

#pragma unroll
    for (int i = 0; i < 8; ++i) {
        const int m = m0 + tx * 8 + i;
        if (m < M) {
            float res[8];
#pragma unroll
            for (int j = 0; j < 8; ++j) {
                float c = acc[i][j] * binv[ty * 8 + j];
                c = fminf(1.f, fmaxf(-1.f, c));
                res[j] = 2.f - sqrtf(fmaxf(0.f, 2.f - 2.f * c));
            }
            float* op = outActs + (size_t)m * HSAE + h0 + ty * 8;
            *(float4*)op       = make_float4(res[0], res[1], res[2], res[3]);
            *(float4*)(op + 4) = make_float4(res[4], res[5], res[6], res[7]);
        }
    }
}

// ---------------- 5. top-32 per row: histogram radix-select ----------------
// acts >= 0 always, so float-bit order == value order. 64-bit key
// (bits<<32)|(16383-idx) reproduces jax.lax.top_k's (value desc, idx asc)
// tie-break exactly; keys are unique, so exact rank = count-of-greater.
constexpr int NBINS = 2048;
constexpr int CAP   = 2048;   // candidate buffer; boundary bin expected ~60-100

__global__ __launch_bounds__(256) void topk_kernel(float* __restrict__ out_buf,
                                                   float* __restrict__ ws) {
    const int r   = blockIdx.x;
    const int tid = threadIdx.x;
    const int wv  = tid >> 6;
    float* row;
    int* idxp; float* valp;
    if (r < NROW_V) {
        row  = out_buf + OUT_LAT_V + (size_t)r * HSAE;
        idxp = (int*)(ws + WS_IDX_V) + (size_t)r * TOPK;
        valp = ws + WS_VAL_V + (size_t)r * TOPK;
    } else {
        const int rr = r - NROW_V;
        row  = out_buf + OUT_LAT_T + (size_t)rr * HSAE;
        idxp = (int*)(ws + WS_IDX_T) + (size_t)rr * TOPK;
        valp = ws + WS_VAL_T + (size_t)rr * TOPK;
    }

    __shared__ unsigned int hist[4][NBINS];       // 32 KB, per-wave copies
    __shared__ unsigned long long cand[CAP];      // 16 KB
    __shared__ int s_ncand;
    __shared__ int s_bin;

    for (int i = tid; i < 4 * NBINS; i += 256) ((unsigned int*)hist)[i] = 0u;
    if (tid == 0) s_ncand = 0;
    __syncthreads();

    // load row (single global read) into 64 statically-indexed registers
    unsigned int bcache[64];
#pragma unroll
    for (int e = 0; e < 16; ++e) {
        const float4 v = *(const float4*)(row + (size_t)e * 1024 + tid * 4);
        bcache[e * 4 + 0] = __float_as_uint(v.x);
        bcache[e * 4 + 1] = __float_as_uint(v.y);
        bcache[e * 4 + 2] = __float_as_uint(v.z);
        bcache[e * 4 + 3] = __float_as_uint(v.w);
    }
    // zero the row now (content lives in regs); scatter happens after barrier
#pragma unroll
    for (int e = 0; e < 16; ++e)
        *(float4*)(row + (size_t)e * 1024 + tid * 4) = make_float4(0.f, 0.f, 0.f, 0.f);

    // per-wave histogram (bin = bits>>19, clamped; clamping only coarsens,
    // exactness is restored by the final candidate rank pass)
#pragma unroll
    for (int e = 0; e < 64; ++e) {
        unsigned int bin = bcache[e] >> 19;
        if (bin > NBINS - 1) bin = NBINS - 1;
        atomicAdd(&hist[wv][bin], 1u);
    }
    __syncthreads();

    // merge per-wave copies into hist[0]
    for (int i = tid; i < NBINS; i += 256)
        hist[0][i] += hist[1][i] + hist[2][i] + hist[3][i];
    __syncthreads();

    // wave 0: hierarchical suffix-count to find the bin holding rank-32
    if (tid < 64) {
        unsigned int csum = 0;
#pragma unroll
        for (int j = 0; j < 32; ++j)                 // bank-rotated: conflict-free
            csum += hist[0][tid * 32 + ((tid + j) & 31)];
        unsigned int suf = csum;                     // inclusive suffix sum over lanes
#pragma unroll
        for (int off = 1; off < 64; off <<= 1) {
            unsigned int o = __shfl_down(suf, off);
            suf += (tid + off < 64) ? o : 0u;
        }
        if (suf >= (unsigned)TOPK && (suf - csum) < (unsigned)TOPK) {
            unsigned int run = suf - csum;           // count in chunks above
            int b = tid * 32 + 31;
            for (; b > tid * 32; --b) {
                const unsigned int h = hist[0][b];
                if (run + h >= (unsigned)TOPK) break;
                run += h;
            }
            s_bin = b;
        }
    }
    __syncthreads();
    const unsigned int B = (unsigned int)s_bin;

    // compact all elements with bin >= B (candidate set covers the full top-32)
#pragma unroll
    for (int e = 0; e < 64; ++e) {
        const unsigned int bits = bcache[e];
        unsigned int bin = bits >> 19;
        if (bin > NBINS - 1) bin = NBINS - 1;
        if (bin >= B) {
            const int slot = atomicAdd(&s_ncand, 1);
            if (slot < CAP) {
                const unsigned int idx = (unsigned)(e >> 2) * 1024u + (unsigned)tid * 4u + (unsigned)(e & 3);
                cand[slot] = ((unsigned long long)bits << 32) | (unsigned long long)(16383u - idx);
            }
        }
    }
    __syncthreads();

    int nc = s_ncand; if (nc > CAP) nc = CAP;
    // exact rank among candidates; rank < 32 -> selected, rank is its slot
    for (int i = tid; i < nc; i += 256) {
        const unsigned long long K = cand[i];
        int rank = 0;
        for (int j = 0; j < nc; ++j) rank += (cand[j] > K) ? 1 : 0;
        if (rank < TOPK) {
            const unsigned int bits = (unsigned int)(K >> 32);
            const int idx = 16383 - (int)(K & 0xFFFFFFFFull);
            const float val = __uint_as_float(bits);
            idxp[rank] = idx;
            valp[rank] = val;
            row[idx]   = val;
        }
    }
}

// ---------------- 6. sparse reconstruction ----------------
__global__ __launch_bounds__(256) void recon_kernel(const float* __restrict__ decw,  // [D, HSAE]
                                                    const float* __restrict__ decb,  // [D]
                                                    const int* __restrict__ idxp,    // [M, 32]
                                                    const float* __restrict__ valp,  // [M, 32]
                                                    float* __restrict__ outp,        // [M, D]
                                                    int M) {
    __shared__ float wrow[HSAE];  // 64 KB
    const int d   = blockIdx.x;
    const int tid = threadIdx.x;
    const float* wr = decw + (size_t)d * HSAE;
    for (int e = 0; e < HSAE / (256 * 4); ++e)
        *(float4*)&wrow[(size_t)(e * 256 + tid) * 4] = *(const float4*)(wr + (size_t)(e * 256 + tid) * 4);
    __syncthreads();
    const float bias = decb[d];
    for (int n = tid; n < M; n += 256) {
        float acc = bias;
#pragma unroll
        for (int k = 0; k < TOPK; ++k)
            acc = fmaf(valp[n * TOPK + k], wrow[idxp[n * TOPK + k]], acc);
        outp[(size_t)n * DD + d] = acc;
    }
}

// ---------------- launch ----------------
extern "C" void kernel_launch(void* const* d_in, const int* in_sizes, int n_in,
                              void* d_out, int out_size, void* d_ws, size_t ws_size,
                              hipStream_t stream) {
    const float* v_pad    = (const float*)d_in[0];
    // d_in[1] v_len: unused by the reference
    const int*   grid_thws = (const int*)d_in[2];
    const float* t_pad    = (const float*)d_in[3];
    const float* t_mask   = (const float*)d_in[4];
    const float* centers  = (const float*)d_in[5];
    const float* enc_v    = (const float*)d_in[6];
    const float* dec_v_w  = (const float*)d_in[7];
    const float* dec_v_b  = (const float*)d_in[8];
    const float* enc_t    = (const float*)d_in[9];
    const float* dec_t_w  = (const float*)d_in[10];
    const float* dec_t_b  = (const float*)d_in[11];
    float* out = (float*)d_out;
    float* ws  = (float*)d_ws;

    pool_t_kernel<<<dim3(NB, 4), 256, 0, stream>>>(t_pad, t_mask, out + OUT_TGLOBAL);
    pool_v_kernel<<<dim3(NB, 4), 256, 0, stream>>>(v_pad, centers, grid_thws, out + OUT_VVIEWS);
    norm_rows_kernel<<<NROW_V + NROW_T, 256, 0, stream>>>(out, ws);
    gemm_acts_kernel<<<dim3(HSAE / BN, NROW_V / BM), 256, 0, stream>>>(ws + WS_VN, enc_v, out + OUT_LAT_V, NROW_V);
    gemm_acts_kernel<<<dim3(HSAE / BN, 1), 256, 0, stream>>>(ws + WS_TN, enc_t, out + OUT_LAT_T, NROW_T);
    topk_kernel<<<NROW_V + NROW_T, 256, 0, stream>>>(out, ws);
    recon_kernel<<<DD, 256, 0, stream>>>(dec_v_w, dec_v_b, (const int*)(ws + WS_IDX_V), ws + WS_VAL_V,
                                         out + OUT_RECON_V, NROW_V);
    recon_kernel<<<DD, 256, 0, stream>>>(dec_t_w, dec_t_b, (const int*)(ws + WS_IDX_T), ws + WS_VAL_T,
                                         out + OUT_RECON_T, NROW_T);
}

// Round 3
// 646.136 us; speedup vs baseline: 2.2117x; 1.5870x over previous
//
#include <hip/hip_runtime.h>
#include <hip/hip_bf16.h>

// ---------------- problem constants (fixed by setup_inputs) ----------------
constexpr int NB    = 64;      // batch
constexpr int LMAX  = 1024;    // max vision tokens
constexpr int DD    = 1024;    // feature dim
constexpr int HSAE  = 16384;   // SAE latent dim
constexpr int TT    = 512;     // text tokens
constexpr int KV    = 8;       // views per batch
constexpr int TOPK  = 32;
constexpr int NROW_V = NB * KV;   // 512
constexpr int NROW_T = NB;        // 64

// output offsets (floats), concatenated in reference return order
constexpr size_t OUT_RECON_V = 0;                                   // [512,1024]
constexpr size_t OUT_VVIEWS  = OUT_RECON_V + (size_t)NROW_V * DD;   // [512,1024]
constexpr size_t OUT_RECON_T = OUT_VVIEWS + (size_t)NROW_V * DD;    // [64,1024]
constexpr size_t OUT_TGLOBAL = OUT_RECON_T + (size_t)NROW_T * DD;   // [64,1024]
constexpr size_t OUT_LAT_V   = OUT_TGLOBAL + (size_t)NROW_T * DD;   // [512,16384]
constexpr size_t OUT_LAT_T   = OUT_LAT_V + (size_t)NROW_V * HSAE;   // [64,16384]

// workspace offsets (floats)
constexpr size_t WS_VN    = 0;                                   // x_n for views [512,1024]
constexpr size_t WS_TN    = WS_VN + (size_t)NROW_V * DD;         // x_n for text  [64,1024]
constexpr size_t WS_IDX_V = WS_TN + (size_t)NROW_T * DD;         // int [512,32]
constexpr size_t WS_VAL_V = WS_IDX_V + (size_t)NROW_V * TOPK;    // f32 [512,32]
constexpr size_t WS_IDX_T = WS_VAL_V + (size_t)NROW_V * TOPK;    // int [64,32]
constexpr size_t WS_VAL_T = WS_IDX_T + (size_t)NROW_T * TOPK;    // f32 [64,32]

// pooling partial-sum scratch lives inside the (not-yet-written) latent output
// regions; the acts GEMM fully overwrites them afterwards.
constexpr int LC  = 8;             // l-chunks for vision pooling
constexpr int LCH = LMAX / LC;     // 128
constexpr int TC  = 8;             // t-chunks for text pooling
constexpr int TCH = TT / TC;       // 64
// within OUT_LAT_V region (8,388,608 floats):
constexpr size_t PV_NUM = 0;                                  // [NB*LC][KV][DD] = 4,194,304
constexpr size_t PV_DEN = (size_t)NB * LC * KV * DD;          // [NB*LC][KV]     = 4,096
// within OUT_LAT_T region (1,048,576 floats):
constexpr size_t PT_NUM = 0;                                  // [NB*TC][DD]     = 524,288
constexpr size_t PT_DEN = (size_t)NB * TC * DD;               // [NB*TC]         = 512

// ---------------- 1a. text pooling: partial sums over t-chunks ----------------
__global__ __launch_bounds__(256) void pool_t_part_kernel(const float* __restrict__ t_pad,
                                                          const float* __restrict__ t_mask,
                                                          float* __restrict__ part) {
    __shared__ float m_s[TCH];
    const int b   = blockIdx.x;
    const int tc  = blockIdx.y;
    const int tid = threadIdx.x;
    const int t0  = tc * TCH;
    if (tid < TCH) m_s[tid] = t_mask[(size_t)b * TT + t0 + tid];
    __syncthreads();
    if (tid == 0) {
        float s = 0.f;
        for (int i = 0; i < TCH; ++i) s += m_s[i];
        part[PT_DEN + (size_t)b * TC + tc] = s;
    }
    const float* tp = t_pad + ((size_t)b * TT + t0) * DD + tid * 4;
    float4 acc = make_float4(0.f, 0.f, 0.f, 0.f);
#pragma unroll 4
    for (int t = 0; t < TCH; ++t) {
        const float4 v = *(const float4*)(tp + (size_t)t * DD);
        const float m = m_s[t];
        acc.x = fmaf(m, v.x, acc.x); acc.y = fmaf(m, v.y, acc.y);
        acc.z = fmaf(m, v.z, acc.z); acc.w = fmaf(m, v.w, acc.w);
    }
    *(float4*)(part + PT_NUM + ((size_t)b * TC + tc) * DD + tid * 4) = acc;
}

// ---------------- 1b. text pooling: combine ----------------
__global__ __launch_bounds__(256) void pool_t_comb_kernel(const float* __restrict__ part,
                                                          float* __restrict__ out_tg) {
    const int b   = blockIdx.x;
    const int tid = threadIdx.x;
    float den = 1e-6f;
    for (int tc = 0; tc < TC; ++tc) den += part[PT_DEN + (size_t)b * TC + tc];
    float4 s = make_float4(0.f, 0.f, 0.f, 0.f);
    for (int tc = 0; tc < TC; ++tc) {
        const float4 p = *(const float4*)(part + PT_NUM + ((size_t)b * TC + tc) * DD + tid * 4);
        s.x += p.x; s.y += p.y; s.z += p.z; s.w += p.w;
    }
    const float inv = 1.f / den;
    *(float4*)(out_tg + (size_t)b * DD + tid * 4) =
        make_float4(s.x * inv, s.y * inv, s.z * inv, s.w * inv);
}

// ---------------- 2a. gaussian view pooling: partial sums over l-chunks ----------------
__global__ __launch_bounds__(256) void pool_v_part_kernel(const float* __restrict__ v_pad,
                                                          const float* __restrict__ centers,
                                                          const int* __restrict__ grid_thws,
                                                          float* __restrict__ part) {
    __shared__ float m_s[LCH][KV];   // 4 KB
    const int b   = blockIdx.x;
    const int lc  = blockIdx.y;
    const int tid = threadIdx.x;
    const int H = grid_thws[1];
    const int W = grid_thws[2];
    int L = H * W; if (L > LMAX) L = LMAX;
    const int l0 = lc * LCH;

    for (int i = tid; i < LCH * KV; i += 256) {
        const int ll = i >> 3, k = i & 7;
        const int l  = l0 + ll;
        float m = 0.f;
        if (l < L) {
            const int iy = l / W, ix = l - iy * W;
            const float gx = (ix + 0.5f) / (float)W;
            const float gy = (iy + 0.5f) / (float)H;
            const float dx = centers[((size_t)b * KV + k) * 2 + 0] - gx;
            const float dy = centers[((size_t)b * KV + k) * 2 + 1] - gy;
            m = expf(-10.f * (dx * dx + dy * dy));
        }
        m_s[ll][k] = m;
    }
    __syncthreads();
    if (tid < KV) {   // deterministic per-chunk denominator partial
        float s = 0.f;
        for (int ll = 0; ll < LCH; ++ll) s += m_s[ll][tid];
        part[PV_DEN + ((size_t)b * LC + lc) * KV + tid] = s;
    }

    const float* vp = v_pad + ((size_t)b * LMAX + l0) * DD + tid * 4;
    float4 acc[KV];
#pragma unroll
    for (int k = 0; k < KV; ++k) acc[k] = make_float4(0.f, 0.f, 0.f, 0.f);
#pragma unroll 4
    for (int ll = 0; ll < LCH; ++ll) {
        const float4 v = *(const float4*)(vp + (size_t)ll * DD);
#pragma unroll
        for (int k = 0; k < KV; ++k) {
            const float m = m_s[ll][k];
            acc[k].x = fmaf(m, v.x, acc[k].x); acc[k].y = fmaf(m, v.y, acc[k].y);
            acc[k].z = fmaf(m, v.z, acc[k].z); acc[k].w = fmaf(m, v.w, acc[k].w);
        }
    }
#pragma unroll
    for (int k = 0; k < KV; ++k)
        *(float4*)(part + PV_NUM + (((size_t)b * LC + lc) * KV + k) * DD + tid * 4) = acc[k];
}

// ---------------- 2b. gaussian view pooling: combine ----------------
__global__ __launch_bounds__(256) void pool_v_comb_kernel(const float* __restrict__ part,
                                                          float* __restrict__ out_views) {
    const int b   = blockIdx.x;
    const int k   = blockIdx.y;
    const int tid = threadIdx.x;
    float den = 1e-6f;
    for (int lc = 0; lc < LC; ++lc) den += part[PV_DEN + ((size_t)b * LC + lc) * KV + k];
    float4 s = make_float4(0.f, 0.f, 0.f, 0.f);
    for (int lc = 0; lc < LC; ++lc) {
        const float4 p = *(const float4*)(part + PV_NUM + (((size_t)b * LC + lc) * KV + k) * DD + tid * 4);
        s.x += p.x; s.y += p.y; s.z += p.z; s.w += p.w;
    }
    const float inv = 1.f / den;
    *(float4*)(out_views + ((size_t)b * KV + k) * DD + tid * 4) =
        make_float4(s.x * inv, s.y * inv, s.z * inv, s.w * inv);
}

// ---------------- 3. row l2-normalize (views + t_global -> ws) ----------------
__global__ __launch_bounds__(256) void norm_rows_kernel(const float* __restrict__ out_buf,
                                                        float* __restrict__ ws) {
    const int r   = blockIdx.x;
    const int tid = threadIdx.x;
    const float* src;
    float* dst;
    if (r < NROW_V) {
        src = out_buf + OUT_VVIEWS + (size_t)r * DD;
        dst = ws + WS_VN + (size_t)r * DD;
    } else {
        src = out_buf + OUT_TGLOBAL + (size_t)(r - NROW_V) * DD;
        dst = ws + WS_TN + (size_t)(r - NROW_V) * DD;
    }
    float4 x = *(const float4*)(src + tid * 4);
    float ss = x.x * x.x + x.y * x.y + x.z * x.z + x.w * x.w;
#pragma unroll
    for (int off = 32; off; off >>= 1) ss += __shfl_down(ss, off);
    __shared__ float wsum[4];
    if ((tid & 63) == 0) wsum[tid >> 6] = ss;
    __syncthreads();
    float tot = wsum[0] + wsum[1] + wsum[2] + wsum[3];
    float scale = 1.f / fmaxf(sqrtf(tot), 1e-12f);
    float4 y;
    y.x = x.x * scale; y.y = x.y * scale; y.z = x.z * scale; y.w = x.w * scale;
    *(float4*)(dst + tid * 4) = y;
}

// ---------------- 4. f32 GEMM -> acts (fused enc-row-norm) ----------------
constexpr int BM = 128, BN = 128, KT = 16;

__global__ __launch_bounds__(256) void gemm_acts_kernel(const float* __restrict__ A,   // [M, D] normalized
                                                        const float* __restrict__ Bm,  // [HSAE, D] raw enc
                                                        float* __restrict__ outActs,   // [M, HSAE]
                                                        int M) {
    __shared__ __align__(16) float As[KT][BM + 4];
    __shared__ __align__(16) float Bs[KT][BN + 4];
    __shared__ float bn_part[BN][2];
    __shared__ float binv[BN];

    const int tid  = threadIdx.x;
    const int h0   = blockIdx.x * BN;
    const int m0   = blockIdx.y * BM;
    const int srow = tid >> 1;             // 0..127
    const int scol = (tid & 1) * 8;        // 0 or 8
    const int tx   = tid & 15;             // m direction
    const int ty   = tid >> 4;             // h direction
    const bool aval = (m0 + srow) < M;
    const float* aptr = A  + (size_t)(m0 + srow) * DD + scol;
    const float* bptr = Bm + (size_t)(h0 + srow) * DD + scol;

    float acc[8][8];
#pragma unroll
    for (int i = 0; i < 8; ++i)
#pragma unroll
        for (int j = 0; j < 8; ++j) acc[i][j] = 0.f;
    float bn = 0.f;

    for (int kt = 0; kt < DD; kt += KT) {
        float4 a0, a1;
        if (aval) {
            a0 = *(const float4*)(aptr + kt);
            a1 = *(const float4*)(aptr + kt + 4);
        } else {
            a0 = make_float4(0.f, 0.f, 0.f, 0.f); a1 = a0;
        }
        const float4 b0 = *(const float4*)(bptr + kt);
        const float4 b1 = *(const float4*)(bptr + kt + 4);
        bn += b0.x * b0.x + b0.y * b0.y + b0.z * b0.z + b0.w * b0.w;
        bn += b1.x * b1.x + b1.y * b1.y + b1.z * b1.z + b1.w * b1.w;

        __syncthreads();
        As[scol + 0][srow] = a0.x; As[scol + 1][srow] = a0.y;
        As[scol + 2][srow] = a0.z; As[scol + 3][srow] = a0.w;
        As[scol + 4][srow] = a1.x; As[scol + 5][srow] = a1.y;
        As[scol + 6][srow] = a1.z; As[scol + 7][srow] = a1.w;
        Bs[scol + 0][srow] = b0.x; Bs[scol + 1][srow] = b0.y;
        Bs[scol + 2][srow] = b0.z; Bs[scol + 3][srow] = b0.w;
        Bs[scol + 4][srow] = b1.x; Bs[scol + 5][srow] = b1.y;
        Bs[scol + 6][srow] = b1.z; Bs[scol + 7][srow] = b1.w;
        __syncthreads();

#pragma unroll
        for (int kk = 0; kk < KT; ++kk) {
            const float4 av0 = *(const float4*)&As[kk][tx * 8];
            const float4 av1 = *(const float4*)&As[kk][tx * 8 + 4];
            const float4 bv0 = *(const float4*)&Bs[kk][ty * 8];
            const float4 bv1 = *(const float4*)&Bs[kk][ty * 8 + 4];
            const float ar[8] = {av0.x, av0.y, av0.z, av0.w, av1.x, av1.y, av1.z, av1.w};
            const float br[8] = {bv0.x, bv0.y, bv0.z, bv0.w, bv1.x, bv1.y, bv1.z, bv1.w};
#pragma unroll
            for (int i = 0; i < 8; ++i)
#pragma unroll
                for (int j = 0; j < 8; ++j)
                    acc[i][j] = fmaf(ar[i], br[j], acc[i][j]);
        }
    }

    bn_part[srow][tid & 1] = bn;
    __syncthreads();
    if (tid < BN) {
        float s = bn_part[tid][0] + bn_part[tid][1];
        binv[tid] = 1.f / fmaxf(sqrtf(s), 1e-12f);
    }
    __syncthreads();

#pragma unroll
    for (int i = 0; i < 8; ++i) {
        const int m = m0 + tx * 8 + i;
        if (m < M) {
            float res[8];
#pragma unroll
            for (int j = 0; j < 8; ++j) {
                float c = acc[i][j] * binv[ty * 8 + j];
                c = fminf(1.f, fmaxf(-1.f, c));
                res[j] = 2.f - sqrtf(fmaxf(0.f, 2.f - 2.f * c));
            }
            float* op = outActs + (size_t)m * HSAE + h0 + ty * 8;
            *(float4*)op       = make_float4(res[0], res[1], res[2], res[3]);
            *(float4*)(op + 4) = make_float4(res[4], res[5], res[6], res[7]);
        }
    }
}

// ---------------- 5. top-32 per row: histogram radix-select ----------------
constexpr int NBINS = 2048;
constexpr int CAP   = 2048;

__global__ __launch_bounds__(256) void topk_kernel(float* __restrict__ out_buf,
                                                   float* __restrict__ ws) {
    const int r   = blockIdx.x;
    const int tid = threadIdx.x;
    const int wv  = tid >> 6;
    float* row;
    int* idxp; float* valp;
    if (r < NROW_V) {
        row  = out_buf + OUT_LAT_V + (size_t)r * HSAE;
        idxp = (int*)(ws + WS_IDX_V) + (size_t)r * TOPK;
        valp = ws + WS_VAL_V + (size_t)r * TOPK;
    } else {
        const int rr = r - NROW_V;
        row  = out_buf + OUT_LAT_T + (size_t)rr * HSAE;
        idxp = (int*)(ws + WS_IDX_T) + (size_t)rr * TOPK;
        valp = ws + WS_VAL_T + (size_t)rr * TOPK;
    }

    __shared__ unsigned int hist[4][NBINS];       // 32 KB, per-wave copies
    __shared__ unsigned long long cand[CAP];      // 16 KB
    __shared__ int s_ncand;
    __shared__ int s_bin;

    for (int i = tid; i < 4 * NBINS; i += 256) ((unsigned int*)hist)[i] = 0u;
    if (tid == 0) s_ncand = 0;
    __syncthreads();

    unsigned int bcache[64];
#pragma unroll
    for (int e = 0; e < 16; ++e) {
        const float4 v = *(const float4*)(row + (size_t)e * 1024 + tid * 4);
        bcache[e * 4 + 0] = __float_as_uint(v.x);
        bcache[e * 4 + 1] = __float_as_uint(v.y);
        bcache[e * 4 + 2] = __float_as_uint(v.z);
        bcache[e * 4 + 3] = __float_as_uint(v.w);
    }
#pragma unroll
    for (int e = 0; e < 16; ++e)
        *(float4*)(row + (size_t)e * 1024 + tid * 4) = make_float4(0.f, 0.f, 0.f, 0.f);

#pragma unroll
    for (int e = 0; e < 64; ++e) {
        unsigned int bin = bcache[e] >> 19;
        if (bin > NBINS - 1) bin = NBINS - 1;
        atomicAdd(&hist[wv][bin], 1u);
    }
    __syncthreads();

    for (int i = tid; i < NBINS; i += 256)
        hist[0][i] += hist[1][i] + hist[2][i] + hist[3][i];
    __syncthreads();

    if (tid < 64) {
        unsigned int csum = 0;
#pragma unroll
        for (int j = 0; j < 32; ++j)
            csum += hist[0][tid * 32 + ((tid + j) & 31)];
        unsigned int suf = csum;
#pragma unroll
        for (int off = 1; off < 64; off <<= 1) {
            unsigned int o = __shfl_down(suf, off);
            suf += (tid + off < 64) ? o : 0u;
        }
        if (suf >= (unsigned)TOPK && (suf - csum) < (unsigned)TOPK) {
            unsigned int run = suf - csum;
            int b = tid * 32 + 31;
            for (; b > tid * 32; --b) {
                const unsigned int h = hist[0][b];
                if (run + h >= (unsigned)TOPK) break;
                run += h;
            }
            s_bin = b;
        }
    }
    __syncthreads();
    const unsigned int B = (unsigned int)s_bin;

#pragma unroll
    for (int e = 0; e < 64; ++e) {
        const unsigned int bits = bcache[e];
        unsigned int bin = bits >> 19;
        if (bin > NBINS - 1) bin = NBINS - 1;
        if (bin >= B) {
            const int slot = atomicAdd(&s_ncand, 1);
            if (slot < CAP) {
                const unsigned int idx = (unsigned)(e >> 2) * 1024u + (unsigned)tid * 4u + (unsigned)(e & 3);
                cand[slot] = ((unsigned long long)bits << 32) | (unsigned long long)(16383u - idx);
            }
        }
    }
    __syncthreads();

    int nc = s_ncand; if (nc > CAP) nc = CAP;
    for (int i = tid; i < nc; i += 256) {
        const unsigned long long K = cand[i];
        int rank = 0;
        for (int j = 0; j < nc; ++j) rank += (cand[j] > K) ? 1 : 0;
        if (rank < TOPK) {
            const unsigned int bits = (unsigned int)(K >> 32);
            const int idx = 16383 - (int)(K & 0xFFFFFFFFull);
            const float val = __uint_as_float(bits);
            idxp[rank] = idx;
            valp[rank] = val;
            row[idx]   = val;
        }
    }
}

// ---------------- 6. sparse reconstruction ----------------
__global__ __launch_bounds__(256) void recon_kernel(const float* __restrict__ decw,  // [D, HSAE]
                                                    const float* __restrict__ decb,  // [D]
                                                    const int* __restrict__ idxp,    // [M, 32]
                                                    const float* __restrict__ valp,  // [M, 32]
                                                    float* __restrict__ outp,        // [M, D]
                                                    int M) {
    __shared__ float wrow[HSAE];  // 64 KB
    const int d   = blockIdx.x;
    const int tid = threadIdx.x;
    const float* wr = decw + (size_t)d * HSAE;
    for (int e = 0; e < HSAE / (256 * 4); ++e)
        *(float4*)&wrow[(size_t)(e * 256 + tid) * 4] = *(const float4*)(wr + (size_t)(e * 256 + tid) * 4);
    __syncthreads();
    const float bias = decb[d];
    for (int n = tid; n < M; n += 256) {
        float acc = bias;
#pragma unroll
        for (int k = 0; k < TOPK; ++k)
            acc = fmaf(valp[n * TOPK + k], wrow[idxp[n * TOPK + k]], acc);
        outp[(size_t)n * DD + d] = acc;
    }
}

// ---------------- launch ----------------
extern "C" void kernel_launch(void* const* d_in, const int* in_sizes, int n_in,
                              void* d_out, int out_size, void* d_ws, size_t ws_size,
                              hipStream_t stream) {
    const float* v_pad    = (const float*)d_in[0];
    // d_in[1] v_len: unused by the reference
    const int*   grid_thws = (const int*)d_in[2];
    const float* t_pad    = (const float*)d_in[3];
    const float* t_mask   = (const float*)d_in[4];
    const float* centers  = (const float*)d_in[5];
    const float* enc_v    = (const float*)d_in[6];
    const float* dec_v_w  = (const float*)d_in[7];
    const float* dec_v_b  = (const float*)d_in[8];
    const float* enc_t    = (const float*)d_in[9];
    const float* dec_t_w  = (const float*)d_in[10];
    const float* dec_t_b  = (const float*)d_in[11];
    float* out = (float*)d_out;
    float* ws  = (float*)d_ws;

    // pooling partials use latent output regions as scratch (overwritten by GEMM later)
    pool_t_part_kernel<<<dim3(NB, TC), 256, 0, stream>>>(t_pad, t_mask, out + OUT_LAT_T);
    pool_t_comb_kernel<<<NB, 256, 0, stream>>>(out + OUT_LAT_T, out + OUT_TGLOBAL);
    pool_v_part_kernel<<<dim3(NB, LC), 256, 0, stream>>>(v_pad, centers, grid_thws, out + OUT_LAT_V);
    pool_v_comb_kernel<<<dim3(NB, KV), 256, 0, stream>>>(out + OUT_LAT_V, out + OUT_VVIEWS);
    norm_rows_kernel<<<NROW_V + NROW_T, 256, 0, stream>>>(out, ws);
    gemm_acts_kernel<<<dim3(HSAE / BN, NROW_V / BM), 256, 0, stream>>>(ws + WS_VN, enc_v, out + OUT_LAT_V, NROW_V);
    gemm_acts_kernel<<<dim3(HSAE / BN, 1), 256, 0, stream>>>(ws + WS_TN, enc_t, out + OUT_LAT_T, NROW_T);
    topk_kernel<<<NROW_V + NROW_T, 256, 0, stream>>>(out, ws);
    recon_kernel<<<DD, 256, 0, stream>>>(dec_v_w, dec_v_b, (const int*)(ws + WS_IDX_V), ws + WS_VAL_V,
                                         out + OUT_RECON_V, NROW_V);
    recon_kernel<<<DD, 256, 0, stream>>>(dec_t_w, dec_t_b, (const int*)(ws + WS_IDX_T), ws + WS_VAL_T,
                                         out + OUT_RECON_T, NROW_T);
}

// Round 5
// 410.701 us; speedup vs baseline: 3.4796x; 1.5733x over previous
//
#include <hip/hip_runtime.h>
#include <hip/hip_bf16.h>

// ---------------- problem constants (fixed by setup_inputs) ----------------
constexpr int NB    = 64;      // batch
constexpr int LMAX  = 1024;    // max vision tokens
constexpr int DD    = 1024;    // feature dim
constexpr int HSAE  = 16384;   // SAE latent dim
constexpr int TT    = 512;     // text tokens
constexpr int KV    = 8;       // views per batch
constexpr int TOPK  = 32;
constexpr int NROW_V = NB * KV;   // 512
constexpr int NROW_T = NB;        // 64

// output offsets (floats), concatenated in reference return order
constexpr size_t OUT_RECON_V = 0;                                   // [512,1024]
constexpr size_t OUT_VVIEWS  = OUT_RECON_V + (size_t)NROW_V * DD;   // [512,1024]
constexpr size_t OUT_RECON_T = OUT_VVIEWS + (size_t)NROW_V * DD;    // [64,1024]
constexpr size_t OUT_TGLOBAL = OUT_RECON_T + (size_t)NROW_T * DD;   // [64,1024]
constexpr size_t OUT_LAT_V   = OUT_TGLOBAL + (size_t)NROW_T * DD;   // [512,16384]
constexpr size_t OUT_LAT_T   = OUT_LAT_V + (size_t)NROW_V * HSAE;   // [64,16384]

// workspace offsets (floats)
constexpr size_t WS_VN     = 0;                                   // x_n views [512,1024]
constexpr size_t WS_TN     = WS_VN + (size_t)NROW_V * DD;         // x_n text  [64,1024]
constexpr size_t WS_IDX_V  = WS_TN + (size_t)NROW_T * DD;         // int [512,32]
constexpr size_t WS_VAL_V  = WS_IDX_V + (size_t)NROW_V * TOPK;    // f32 [512,32]
constexpr size_t WS_IDX_T  = WS_VAL_V + (size_t)NROW_V * TOPK;    // int [64,32]
constexpr size_t WS_VAL_T  = WS_IDX_T + (size_t)NROW_T * TOPK;    // f32 [64,32]
constexpr size_t WS_BINV_V = WS_VAL_T + (size_t)NROW_T * TOPK;    // f32 [16384]
constexpr size_t WS_BINV_T = WS_BINV_V + (size_t)HSAE;            // f32 [16384]

// pooling partial-sum scratch inside the (not-yet-written) latent regions
constexpr int LC  = 8;             // l-chunks for vision pooling
constexpr int LCH = LMAX / LC;     // 128
constexpr int TC  = 8;             // t-chunks for text pooling
constexpr int TCH = TT / TC;       // 64
constexpr size_t PV_NUM = 0;                                  // [NB*LC][KV][DD]
constexpr size_t PV_DEN = (size_t)NB * LC * KV * DD;          // [NB*LC][KV]
constexpr size_t PT_NUM = 0;                                  // [NB*TC][DD]
constexpr size_t PT_DEN = (size_t)NB * TC * DD;               // [NB*TC]

typedef __attribute__((ext_vector_type(8))) short bf16x8;
typedef __attribute__((ext_vector_type(4))) float f32x4;

__device__ inline unsigned short f2bf_rn(float x) {
    unsigned u = __float_as_uint(x);
    return (unsigned short)((u + 0x7FFFu + ((u >> 16) & 1u)) >> 16);
}
__device__ inline double shfl_down_dbl(double x, int off) {
    long long l = __double_as_longlong(x);
    int lo = (int)(l & 0xffffffffll), hi = (int)(l >> 32);
    lo = __shfl_down(lo, off); hi = __shfl_down(hi, off);
    return __longlong_as_double(((long long)hi << 32) | (unsigned long long)(unsigned int)lo);
}

// ---------------- 1a. text pooling: partial sums over t-chunks ----------------
__global__ __launch_bounds__(256) void pool_t_part_kernel(const float* __restrict__ t_pad,
                                                          const float* __restrict__ t_mask,
                                                          float* __restrict__ part) {
    __shared__ float m_s[TCH];
    const int b   = blockIdx.x;
    const int tc  = blockIdx.y;
    const int tid = threadIdx.x;
    const int t0  = tc * TCH;
    if (tid < TCH) m_s[tid] = t_mask[(size_t)b * TT + t0 + tid];
    __syncthreads();
    if (tid == 0) {
        float s = 0.f;
        for (int i = 0; i < TCH; ++i) s += m_s[i];
        part[PT_DEN + (size_t)b * TC + tc] = s;
    }
    const float* tp = t_pad + ((size_t)b * TT + t0) * DD + tid * 4;
    float4 acc = make_float4(0.f, 0.f, 0.f, 0.f);
#pragma unroll 4
    for (int t = 0; t < TCH; ++t) {
        const float4 v = *(const float4*)(tp + (size_t)t * DD);
        const float m = m_s[t];
        acc.x = fmaf(m, v.x, acc.x); acc.y = fmaf(m, v.y, acc.y);
        acc.z = fmaf(m, v.z, acc.z); acc.w = fmaf(m, v.w, acc.w);
    }
    *(float4*)(part + PT_NUM + ((size_t)b * TC + tc) * DD + tid * 4) = acc;
}

// ---------------- 1b. text pooling: combine ----------------
__global__ __launch_bounds__(256) void pool_t_comb_kernel(const float* __restrict__ part,
                                                          float* __restrict__ out_tg) {
    const int b   = blockIdx.x;
    const int tid = threadIdx.x;
    float den = 1e-6f;
    for (int tc = 0; tc < TC; ++tc) den += part[PT_DEN + (size_t)b * TC + tc];
    float4 s = make_float4(0.f, 0.f, 0.f, 0.f);
    for (int tc = 0; tc < TC; ++tc) {
        const float4 p = *(const float4*)(part + PT_NUM + ((size_t)b * TC + tc) * DD + tid * 4);
        s.x += p.x; s.y += p.y; s.z += p.z; s.w += p.w;
    }
    const float inv = 1.f / den;
    *(float4*)(out_tg + (size_t)b * DD + tid * 4) =
        make_float4(s.x * inv, s.y * inv, s.z * inv, s.w * inv);
}

// ---------------- 2a. gaussian view pooling: partial sums ----------------
__global__ __launch_bounds__(256) void pool_v_part_kernel(const float* __restrict__ v_pad,
                                                          const float* __restrict__ centers,
                                                          const int* __restrict__ grid_thws,
                                                          float* __restrict__ part) {
    __shared__ float m_s[LCH][KV];   // 4 KB
    const int b   = blockIdx.x;
    const int lc  = blockIdx.y;
    const int tid = threadIdx.x;
    const int H = grid_thws[1];
    const int W = grid_thws[2];
    int L = H * W; if (L > LMAX) L = LMAX;
    const int l0 = lc * LCH;

    for (int i = tid; i < LCH * KV; i += 256) {
        const int ll = i >> 3, k = i & 7;
        const int l  = l0 + ll;
        float m = 0.f;
        if (l < L) {
            const int iy = l / W, ix = l - iy * W;
            const float gx = (ix + 0.5f) / (float)W;
            const float gy = (iy + 0.5f) / (float)H;
            const float dx = centers[((size_t)b * KV + k) * 2 + 0] - gx;
            const float dy = centers[((size_t)b * KV + k) * 2 + 1] - gy;
            m = expf(-10.f * (dx * dx + dy * dy));
        }
        m_s[ll][k] = m;
    }
    __syncthreads();
    if (tid < KV) {
        float s = 0.f;
        for (int ll = 0; ll < LCH; ++ll) s += m_s[ll][tid];
        part[PV_DEN + ((size_t)b * LC + lc) * KV + tid] = s;
    }

    const float* vp = v_pad + ((size_t)b * LMAX + l0) * DD + tid * 4;
    float4 acc[KV];
#pragma unroll
    for (int k = 0; k < KV; ++k) acc[k] = make_float4(0.f, 0.f, 0.f, 0.f);
#pragma unroll 4
    for (int ll = 0; ll < LCH; ++ll) {
        const float4 v = *(const float4*)(vp + (size_t)ll * DD);
#pragma unroll
        for (int k = 0; k < KV; ++k) {
            const float m = m_s[ll][k];
            acc[k].x = fmaf(m, v.x, acc[k].x); acc[k].y = fmaf(m, v.y, acc[k].y);
            acc[k].z = fmaf(m, v.z, acc[k].z); acc[k].w = fmaf(m, v.w, acc[k].w);
        }
    }
#pragma unroll
    for (int k = 0; k < KV; ++k)
        *(float4*)(part + PV_NUM + (((size_t)b * LC + lc) * KV + k) * DD + tid * 4) = acc[k];
}

// ---------------- 2b. gaussian view pooling: combine ----------------
__global__ __launch_bounds__(256) void pool_v_comb_kernel(const float* __restrict__ part,
                                                          float* __restrict__ out_views) {
    const int b   = blockIdx.x;
    const int k   = blockIdx.y;
    const int tid = threadIdx.x;
    float den = 1e-6f;
    for (int lc = 0; lc < LC; ++lc) den += part[PV_DEN + ((size_t)b * LC + lc) * KV + k];
    float4 s = make_float4(0.f, 0.f, 0.f, 0.f);
    for (int lc = 0; lc < LC; ++lc) {
        const float4 p = *(const float4*)(part + PV_NUM + (((size_t)b * LC + lc) * KV + k) * DD + tid * 4);
        s.x += p.x; s.y += p.y; s.z += p.z; s.w += p.w;
    }
    const float inv = 1.f / den;
    *(float4*)(out_views + ((size_t)b * KV + k) * DD + tid * 4) =
        make_float4(s.x * inv, s.y * inv, s.z * inv, s.w * inv);
}

// ---------------- 3. row l2-normalize (views + t_global -> ws) ----------------
__global__ __launch_bounds__(256) void norm_rows_kernel(const float* __restrict__ out_buf,
                                                        float* __restrict__ ws) {
    const int r   = blockIdx.x;
    const int tid = threadIdx.x;
    const float* src;
    float* dst;
    if (r < NROW_V) {
        src = out_buf + OUT_VVIEWS + (size_t)r * DD;
        dst = ws + WS_VN + (size_t)r * DD;
    } else {
        src = out_buf + OUT_TGLOBAL + (size_t)(r - NROW_V) * DD;
        dst = ws + WS_TN + (size_t)(r - NROW_V) * DD;
    }
    float4 x = *(const float4*)(src + tid * 4);
    float ss = x.x * x.x + x.y * x.y + x.z * x.z + x.w * x.w;
#pragma unroll
    for (int off = 32; off; off >>= 1) ss += __shfl_down(ss, off);
    __shared__ float wsum[4];
    if ((tid & 63) == 0) wsum[tid >> 6] = ss;
    __syncthreads();
    float tot = wsum[0] + wsum[1] + wsum[2] + wsum[3];
    float scale = 1.f / fmaxf(sqrtf(tot), 1e-12f);
    float4 y;
    y.x = x.x * scale; y.y = x.y * scale; y.z = x.z * scale; y.w = x.w * scale;
    *(float4*)(dst + tid * 4) = y;
}

// ---------------- 3b. enc row inverse norms ----------------
__global__ __launch_bounds__(256) void enc_norm_kernel(const float* __restrict__ enc,
                                                       float* __restrict__ binv) {
    const int row  = blockIdx.x * 4 + (threadIdx.x >> 6);
    const int lane = threadIdx.x & 63;
    const float* p = enc + (size_t)row * DD;
    float ss = 0.f;
#pragma unroll
    for (int i = 0; i < 4; ++i) {
        const float4 v = *(const float4*)(p + lane * 4 + i * 256);
        ss += v.x * v.x + v.y * v.y + v.z * v.z + v.w * v.w;
    }
#pragma unroll
    for (int off = 32; off; off >>= 1) ss += __shfl_down(ss, off);
    if (lane == 0) binv[row] = 1.f / fmaxf(sqrtf(ss), 1e-12f);
}

// ---------------- 4. split-bf16 MFMA GEMM -> acts ----------------
// C[m,h] = acts(clip((x_n[m,:].enc[h,:]) * binv[h]))
// x = hi + lo (two bf16); x.y ~= hi.hi + hi.lo + lo.hi  (3 MFMA passes)
constexpr int GBM = 128, GBN = 128, GBK = 64;

// fragment-ordered LDS offset (in shorts), with XOR swizzle on the row16 slot
__device__ inline int fragoff(int sub, int g, int r16) {
    return (((sub * 8 + g) * 16) + (r16 ^ ((g & 7) << 1))) * 8;
}

__global__ __launch_bounds__(256) void gemm_acts_mfma(const float* __restrict__ A,    // [M, D] normalized
                                                      const float* __restrict__ Bm,   // [HSAE, D] raw enc
                                                      const float* __restrict__ binvp,// [HSAE]
                                                      float* __restrict__ outActs,    // [M, HSAE]
                                                      int M) {
    __shared__ short Ah[GBM * GBK], Al[GBM * GBK];   // 16 KB each
    __shared__ short Bh[GBN * GBK], Bl[GBN * GBK];   // 16 KB each
    __shared__ float binv_s[GBN];

    const int tid  = threadIdx.x;
    const int lane = tid & 63;
    const int wv   = tid >> 6;       // 0..3
    const int wm   = wv & 1;         // wave m-tile (64 rows)
    const int wn   = wv >> 1;        // wave n-tile (64 cols)
    const int h0   = blockIdx.x * GBN;
    const int m0   = blockIdx.y * GBM;

    if (tid < GBN) binv_s[tid] = binvp[h0 + tid];

    f32x4 acc[4][4];
#pragma unroll
    for (int mi = 0; mi < 4; ++mi)
#pragma unroll
        for (int ni = 0; ni < 4; ++ni) acc[mi][ni] = (f32x4){0.f, 0.f, 0.f, 0.f};

    for (int kt = 0; kt < DD; kt += GBK) {
        __syncthreads();
        // stage: 2048 (row,kslot) tasks, 8 per thread; convert f32 -> hi/lo bf16
#pragma unroll
        for (int rt = 0; rt < 8; ++rt) {
            const int task = rt * 256 + tid;
            const int row  = task >> 3;     // 0..127 A rows, 128..255 B rows
            const int ks   = task & 7;
            const float* src;
            bool valid = true;
            int lr;
            if (row < GBM) {
                lr = row;
                valid = (m0 + row) < M;
                src = A + (size_t)(m0 + row) * DD + kt + ks * 8;
            } else {
                lr = row - GBM;
                src = Bm + (size_t)(h0 + lr) * DD + kt + ks * 8;
            }
            float4 v0, v1;
            if (valid) { v0 = *(const float4*)src; v1 = *(const float4*)(src + 4); }
            else { v0 = make_float4(0.f, 0.f, 0.f, 0.f); v1 = v0; }
            const float f[8] = {v0.x, v0.y, v0.z, v0.w, v1.x, v1.y, v1.z, v1.w};
            bf16x8 hv, lv;
#pragma unroll
            for (int j = 0; j < 8; ++j) {
                const unsigned short hb = f2bf_rn(f[j]);
                const float hf = __uint_as_float((unsigned)hb << 16);
                hv[j] = (short)hb;
                lv[j] = (short)f2bf_rn(f[j] - hf);
            }
            const int off = fragoff(lr >> 4, ks, lr & 15);
            if (row < GBM) { *(bf16x8*)&Ah[off] = hv; *(bf16x8*)&Al[off] = lv; }
            else           { *(bf16x8*)&Bh[off] = hv; *(bf16x8*)&Bl[off] = lv; }
        }
        __syncthreads();

#pragma unroll
        for (int s = 0; s < 2; ++s) {      // two K=32 sub-steps per BK=64
            bf16x8 ah[4], al[4], bh[4], bl[4];
            const int g = s * 4 + (lane >> 4);
            const int r16 = lane & 15;
#pragma unroll
            for (int t = 0; t < 4; ++t) {
                const int ao = fragoff(wm * 4 + t, g, r16);
                ah[t] = *(const bf16x8*)&Ah[ao];
                al[t] = *(const bf16x8*)&Al[ao];
                const int bo = fragoff(wn * 4 + t, g, r16);
                bh[t] = *(const bf16x8*)&Bh[bo];
                bl[t] = *(const bf16x8*)&Bl[bo];
            }
#pragma unroll
            for (int mi = 0; mi < 4; ++mi)
#pragma unroll
                for (int ni = 0; ni < 4; ++ni) {
                    acc[mi][ni] = __builtin_amdgcn_mfma_f32_16x16x32_bf16(ah[mi], bh[ni], acc[mi][ni], 0, 0, 0);
                    acc[mi][ni] = __builtin_amdgcn_mfma_f32_16x16x32_bf16(ah[mi], bl[ni], acc[mi][ni], 0, 0, 0);
                    acc[mi][ni] = __builtin_amdgcn_mfma_f32_16x16x32_bf16(al[mi], bh[ni], acc[mi][ni], 0, 0, 0);
                }
        }
    }

    // epilogue: scale by binv, clip, acts transform, store f32
#pragma unroll
    for (int mi = 0; mi < 4; ++mi)
#pragma unroll
        for (int ni = 0; ni < 4; ++ni) {
            const int hl = wn * 64 + ni * 16 + (lane & 15);
            const float bi = binv_s[hl];
#pragma unroll
            for (int j = 0; j < 4; ++j) {
                const int m = m0 + wm * 64 + mi * 16 + (lane >> 4) * 4 + j;
                if (m < M) {
                    float c = acc[mi][ni][j] * bi;
                    c = fminf(1.f, fmaxf(-1.f, c));
                    outActs[(size_t)m * HSAE + h0 + hl] = 2.f - sqrtf(fmaxf(0.f, 2.f - 2.f * c));
                }
            }
        }
}

// ---------------- 5. top-32: two-level histogram screen + exact boundary re-rank ----------------
// Coarse bin = bits>>19 (4 mantissa bits); fine sub-bin = (bits>>11)&255 (next 8).
// One fine bin (~1.2e-4 at v~0.65) >> RANKEPS, so the S0-1 margin provably covers
// the +-RANKEPS ambiguity band that gets re-ranked in f64.
constexpr int NBINS = 2048;
constexpr int NFINE = 256;
constexpr int CAP   = 512;     // expected candidates ~35-100
constexpr float RANKEPS = 4e-6f;   // ~9 sigma of split-bf16 GEMM acts error

__global__ __launch_bounds__(256) void topk_kernel(float* __restrict__ out_buf,
                                                   float* __restrict__ ws,
                                                   const float* __restrict__ enc_v,
                                                   const float* __restrict__ enc_t) {
    const int r    = blockIdx.x;
    const int tid  = threadIdx.x;
    const int wv   = tid >> 6;
    const int lane = tid & 63;
    float* row;
    int* idxp; float* valp;
    const float* xn; const float* enc; const float* binv;
    if (r < NROW_V) {
        row  = out_buf + OUT_LAT_V + (size_t)r * HSAE;
        idxp = (int*)(ws + WS_IDX_V) + (size_t)r * TOPK;
        valp = ws + WS_VAL_V + (size_t)r * TOPK;
        xn   = ws + WS_VN + (size_t)r * DD;
        enc  = enc_v; binv = ws + WS_BINV_V;
    } else {
        const int rr = r - NROW_V;
        row  = out_buf + OUT_LAT_T + (size_t)rr * HSAE;
        idxp = (int*)(ws + WS_IDX_T) + (size_t)rr * TOPK;
        valp = ws + WS_VAL_T + (size_t)rr * TOPK;
        xn   = ws + WS_TN + (size_t)rr * DD;
        enc  = enc_t; binv = ws + WS_BINV_T;
    }

    __shared__ unsigned int hist[4][NBINS];       // 32 KB
    __shared__ unsigned int fine[4][NFINE];       // 4 KB
    __shared__ float xs[DD];                      // 4 KB
    __shared__ unsigned long long cand[CAP];      // 4 KB
    __shared__ unsigned long long ord[CAP];       // 4 KB
    __shared__ double bval[64];
    __shared__ int    bidx[64];
    __shared__ int s_ncand, s_bin, s_cntgt, s_sub, s_A, s_E;

    for (int i = tid; i < 4 * NBINS; i += 256) ((unsigned int*)hist)[i] = 0u;
    for (int i = tid; i < 4 * NFINE; i += 256) ((unsigned int*)fine)[i] = 0u;
    if (tid == 0) { s_ncand = 0; }
    *(float4*)&xs[tid * 4] = *(const float4*)&xn[tid * 4];

    unsigned int bcache[64];
#pragma unroll
    for (int e = 0; e < 16; ++e) {
        const float4 v = *(const float4*)(row + (size_t)e * 1024 + tid * 4);
        bcache[e * 4 + 0] = __float_as_uint(v.x);
        bcache[e * 4 + 1] = __float_as_uint(v.y);
        bcache[e * 4 + 2] = __float_as_uint(v.z);
        bcache[e * 4 + 3] = __float_as_uint(v.w);
    }
#pragma unroll
    for (int e = 0; e < 16; ++e)
        *(float4*)(row + (size_t)e * 1024 + tid * 4) = make_float4(0.f, 0.f, 0.f, 0.f);
    __syncthreads();

    // ---- coarse histogram ----
#pragma unroll
    for (int e = 0; e < 64; ++e) {
        unsigned int bin = bcache[e] >> 19;
        if (bin > NBINS - 1) bin = NBINS - 1;
        atomicAdd(&hist[wv][bin], 1u);
    }
    __syncthreads();
    for (int i = tid; i < NBINS; i += 256)
        hist[0][i] += hist[1][i] + hist[2][i] + hist[3][i];
    __syncthreads();

    // ---- coarse boundary bin B0 + count strictly above it ----
    if (tid < 64) {
        unsigned int csum = 0;
#pragma unroll
        for (int j = 0; j < 32; ++j)
            csum += hist[0][tid * 32 + ((tid + j) & 31)];
        unsigned int suf = csum;
#pragma unroll
        for (int off = 1; off < 64; off <<= 1) {
            unsigned int o = __shfl_down(suf, off);
            suf += (tid + off < 64) ? o : 0u;
        }
        if (suf >= (unsigned)TOPK && (suf - csum) < (unsigned)TOPK) {
            unsigned int run = suf - csum;
            int b = tid * 32 + 31;
            for (; b > tid * 32; --b) {
                const unsigned int h = hist[0][b];
                if (run + h >= (unsigned)TOPK) break;
                run += h;
            }
            s_bin = b; s_cntgt = (int)run;
        }
    }
    __syncthreads();
    const unsigned int B0 = (unsigned int)s_bin;
    const int cnt_gt = s_cntgt;            // 0 <= cnt_gt < 32
    const int r0 = TOPK - cnt_gt;          // local rank needed inside B0

    // ---- fine histogram over B0's elements ----
#pragma unroll
    for (int e = 0; e < 64; ++e) {
        const unsigned int bits = bcache[e];
        unsigned int bin = bits >> 19;
        if (bin > NBINS - 1) bin = NBINS - 1;
        if (bin == B0) atomicAdd(&fine[wv][(bits >> 11) & 255u], 1u);
    }
    __syncthreads();
    for (int i = tid; i < NFINE; i += 256)
        fine[0][i] += fine[1][i] + fine[2][i] + fine[3][i];
    __syncthreads();

    // ---- fine boundary sub-bin S0 (contains local rank r0) ----
    if (tid < 64) {
        unsigned int csum = fine[0][tid * 4] + fine[0][tid * 4 + 1] +
                            fine[0][tid * 4 + 2] + fine[0][tid * 4 + 3];
        unsigned int suf = csum;
#pragma unroll
        for (int off = 1; off < 64; off <<= 1) {
            unsigned int o = __shfl_down(suf, off);
            suf += (tid + off < 64) ? o : 0u;
        }
        if (suf >= (unsigned)r0 && (suf - csum) < (unsigned)r0) {
            unsigned int run = suf - csum;
            int b = tid * 4 + 3;
            for (; b > tid * 4; --b) {
                const unsigned int h = fine[0][b];
                if (run + h >= (unsigned)r0) break;
                run += h;
            }
            s_sub = b;
        }
    }
    __syncthreads();
    const unsigned int S0m = (s_sub > 0) ? (unsigned)(s_sub - 1) : 0u;  // one FINE bin margin

    // ---- compact candidates: (bin > B0) || (bin == B0 && sub >= S0m) ----
#pragma unroll
    for (int e = 0; e < 64; ++e) {
        const unsigned int bits = bcache[e];
        unsigned int bin = bits >> 19;
        if (bin > NBINS - 1) bin = NBINS - 1;
        if (bin > B0 || (bin == B0 && ((bits >> 11) & 255u) >= S0m)) {
            const int slot = atomicAdd(&s_ncand, 1);
            if (slot < CAP) {
                const unsigned int idx = (unsigned)(e >> 2) * 1024u + (unsigned)tid * 4u + (unsigned)(e & 3);
                cand[slot] = ((unsigned long long)bits << 32) | (unsigned long long)(16383u - idx);
            }
        }
    }
    __syncthreads();
    const int nc = (s_ncand < CAP) ? s_ncand : CAP;

    // exact rank among candidates by GEMM value (unique keys) -> ordered list
    for (int i = tid; i < nc; i += 256) {
        const unsigned long long K = cand[i];
        int rank = 0;
        for (int j = 0; j < nc; ++j) rank += (cand[j] > K) ? 1 : 0;
        ord[rank] = K;
    }
    if (tid == 0) { s_A = nc; s_E = nc; }
    __syncthreads();

    const float Tv = __uint_as_float((unsigned)(ord[31] >> 32));  // 32nd GEMM value
    for (int i = tid; i < nc; i += 256) {
        const float v = __uint_as_float((unsigned)(ord[i] >> 32));
        if (v <= Tv + RANKEPS) atomicMin(&s_A, i);   // first possibly-ambiguous
        if (v <  Tv - RANKEPS) atomicMin(&s_E, i);   // first certainly-out
    }
    __syncthreads();
    const int A = s_A;                         // ranks [0,A): certainly in (A<=31)
    int E = s_E; if (E > A + 64) E = A + 64;   // band ranks [A,E)
    const int nb = E - A;

    // f64 recompute of the ambiguous band (typically 1-3 elements)
    for (int t = A + wv; t < E; t += 4) {
        const int idx = 16383 - (int)(ord[t] & 0xffffffffull);
        const float* er = enc + (size_t)idx * DD;
        double s = 0.0;
#pragma unroll
        for (int i = 0; i < 16; ++i) {
            const int j = lane + i * 64;
            s = fma((double)xs[j], (double)er[j], s);
        }
#pragma unroll
        for (int off = 32; off; off >>= 1) s += shfl_down_dbl(s, off);
        if (lane == 0) {
            double c = s * (double)binv[idx];
            c = fmin(1.0, fmax(-1.0, c));
            bval[t - A] = 2.0 - sqrt(fmax(0.0, 2.0 - 2.0 * c));
            bidx[t - A] = idx;
        }
    }
    __syncthreads();

    // emit certain winners (ranks [0,A))
    for (int i = tid; i < A; i += 256) {
        const int idx  = 16383 - (int)(ord[i] & 0xffffffffull);
        const float v  = __uint_as_float((unsigned)(ord[i] >> 32));
        idxp[i] = idx; valp[i] = v; row[idx] = v;
    }
    // emit band winners by exact f64 order (slots [A,32))
    for (int t = tid; t < nb; t += 256) {
        int fr = 0;
        for (int u = 0; u < nb; ++u)
            if (bval[u] > bval[t] || (bval[u] == bval[t] && bidx[u] < bidx[t])) fr++;
        const int slot = A + fr;
        if (slot < TOPK) {
            const float v = (float)bval[t];
            idxp[slot] = bidx[t]; valp[slot] = v; row[bidx[t]] = v;
        }
    }
}

// ---------------- 6. sparse reconstruction ----------------
__global__ __launch_bounds__(256) void recon_kernel(const float* __restrict__ decw,  // [D, HSAE]
                                                    const float* __restrict__ decb,  // [D]
                                                    const int* __restrict__ idxp,    // [M, 32]
                                                    const float* __restrict__ valp,  // [M, 32]
                                                    float* __restrict__ outp,        // [M, D]
                                                    int M) {
    __shared__ float wrow[HSAE];  // 64 KB
    const int d   = blockIdx.x;
    const int tid = threadIdx.x;
    const float* wr = decw + (size_t)d * HSAE;
    for (int e = 0; e < HSAE / (256 * 4); ++e)
        *(float4*)&wrow[(size_t)(e * 256 + tid) * 4] = *(const float4*)(wr + (size_t)(e * 256 + tid) * 4);
    __syncthreads();
    const float bias = decb[d];
    for (int n = tid; n < M; n += 256) {
        float acc = bias;
#pragma unroll
        for (int k = 0; k < TOPK; ++k)
            acc = fmaf(valp[n * TOPK + k], wrow[idxp[n * TOPK + k]], acc);
        outp[(size_t)n * DD + d] = acc;
    }
}

// ---------------- launch ----------------
extern "C" void kernel_launch(void* const* d_in, const int* in_sizes, int n_in,
                              void* d_out, int out_size, void* d_ws, size_t ws_size,
                              hipStream_t stream) {
    const float* v_pad    = (const float*)d_in[0];
    // d_in[1] v_len: unused by the reference
    const int*   grid_thws = (const int*)d_in[2];
    const float* t_pad    = (const float*)d_in[3];
    const float* t_mask   = (const float*)d_in[4];
    const float* centers  = (const float*)d_in[5];
    const float* enc_v    = (const float*)d_in[6];
    const float* dec_v_w  = (const float*)d_in[7];
    const float* dec_v_b  = (const float*)d_in[8];
    const float* enc_t    = (const float*)d_in[9];
    const float* dec_t_w  = (const float*)d_in[10];
    const float* dec_t_b  = (const float*)d_in[11];
    float* out = (float*)d_out;
    float* ws  = (float*)d_ws;

    pool_t_part_kernel<<<dim3(NB, TC), 256, 0, stream>>>(t_pad, t_mask, out + OUT_LAT_T);
    pool_t_comb_kernel<<<NB, 256, 0, stream>>>(out + OUT_LAT_T, out + OUT_TGLOBAL);
    pool_v_part_kernel<<<dim3(NB, LC), 256, 0, stream>>>(v_pad, centers, grid_thws, out + OUT_LAT_V);
    pool_v_comb_kernel<<<dim3(NB, KV), 256, 0, stream>>>(out + OUT_LAT_V, out + OUT_VVIEWS);
    norm_rows_kernel<<<NROW_V + NROW_T, 256, 0, stream>>>(out, ws);
    enc_norm_kernel<<<HSAE / 4, 256, 0, stream>>>(enc_v, ws + WS_BINV_V);
    enc_norm_kernel<<<HSAE / 4, 256, 0, stream>>>(enc_t, ws + WS_BINV_T);
    gemm_acts_mfma<<<dim3(HSAE / GBN, NROW_V / GBM), 256, 0, stream>>>(ws + WS_VN, enc_v, ws + WS_BINV_V,
                                                                      out + OUT_LAT_V, NROW_V);
    gemm_acts_mfma<<<dim3(HSAE / GBN, 1), 256, 0, stream>>>(ws + WS_TN, enc_t, ws + WS_BINV_T,
                                                            out + OUT_LAT_T, NROW_T);
    topk_kernel<<<NROW_V + NROW_T, 256, 0, stream>>>(out, ws, enc_v, enc_t);
    recon_kernel<<<DD, 256, 0, stream>>>(dec_v_w, dec_v_b, (const int*)(ws + WS_IDX_V), ws + WS_VAL_V,
                                         out + OUT_RECON_V, NROW_V);
    recon_kernel<<<DD, 256, 0, stream>>>(dec_t_w, dec_t_b, (const int*)(ws + WS_IDX_T), ws + WS_VAL_T,
                                         out + OUT_RECON_T, NROW_T);
}

// Round 6
// 388.385 us; speedup vs baseline: 3.6795x; 1.0575x over previous
//
#include <hip/hip_runtime.h>
#include <hip/hip_bf16.h>

// ---------------- problem constants (fixed by setup_inputs) ----------------
constexpr int NB    = 64;      // batch
constexpr int LMAX  = 1024;    // max vision tokens
constexpr int DD    = 1024;    // feature dim
constexpr int HSAE  = 16384;   // SAE latent dim
constexpr int TT    = 512;     // text tokens
constexpr int KV    = 8;       // views per batch
constexpr int TOPK  = 32;
constexpr int NROW_V = NB * KV;   // 512
constexpr int NROW_T = NB;        // 64

// output offsets (floats), concatenated in reference return order
constexpr size_t OUT_RECON_V = 0;                                   // [512,1024]
constexpr size_t OUT_VVIEWS  = OUT_RECON_V + (size_t)NROW_V * DD;   // [512,1024]
constexpr size_t OUT_RECON_T = OUT_VVIEWS + (size_t)NROW_V * DD;    // [64,1024]
constexpr size_t OUT_TGLOBAL = OUT_RECON_T + (size_t)NROW_T * DD;   // [64,1024]
constexpr size_t OUT_LAT_V   = OUT_TGLOBAL + (size_t)NROW_T * DD;   // [512,16384]
constexpr size_t OUT_LAT_T   = OUT_LAT_V + (size_t)NROW_V * HSAE;   // [64,16384]

// workspace offsets (floats)
constexpr size_t WS_VN     = 0;                                   // x_n views [512,1024]
constexpr size_t WS_TN     = WS_VN + (size_t)NROW_V * DD;         // x_n text  [64,1024]
constexpr size_t WS_IDX_V  = WS_TN + (size_t)NROW_T * DD;         // int [512,32]
constexpr size_t WS_VAL_V  = WS_IDX_V + (size_t)NROW_V * TOPK;    // f32 [512,32]
constexpr size_t WS_IDX_T  = WS_VAL_V + (size_t)NROW_V * TOPK;    // int [64,32]
constexpr size_t WS_VAL_T  = WS_IDX_T + (size_t)NROW_T * TOPK;    // f32 [64,32]
constexpr size_t WS_BINV_V = WS_VAL_T + (size_t)NROW_T * TOPK;    // f32 [16384]
constexpr size_t WS_BINV_T = WS_BINV_V + (size_t)HSAE;            // f32 [16384]
// pre-converted x_n hi/lo bf16 planes (linear [row][k], shorts)
constexpr size_t WS_AHI_V  = WS_BINV_T + (size_t)HSAE;                 // 512*1024 shorts
constexpr size_t WS_ALO_V  = WS_AHI_V + (size_t)NROW_V * DD / 2;
constexpr size_t WS_AHI_T  = WS_ALO_V + (size_t)NROW_V * DD / 2;       // 64*1024 shorts
constexpr size_t WS_ALO_T  = WS_AHI_T + (size_t)NROW_T * DD / 2;

// pooling partial-sum scratch inside the (not-yet-written) latent regions
constexpr int LC  = 8;             // l-chunks for vision pooling
constexpr int LCH = LMAX / LC;     // 128
constexpr int TC  = 8;             // t-chunks for text pooling
constexpr int TCH = TT / TC;       // 64
constexpr size_t PV_NUM = 0;                                  // [NB*LC][KV][DD]
constexpr size_t PV_DEN = (size_t)NB * LC * KV * DD;          // [NB*LC][KV]
constexpr size_t PT_NUM = 0;                                  // [NB*TC][DD]
constexpr size_t PT_DEN = (size_t)NB * TC * DD;               // [NB*TC]

typedef __attribute__((ext_vector_type(8))) short bf16x8;
typedef __attribute__((ext_vector_type(4))) short s16x4;
typedef __attribute__((ext_vector_type(4))) float f32x4;

__device__ inline unsigned short f2bf_rn(float x) {
    unsigned u = __float_as_uint(x);
    return (unsigned short)((u + 0x7FFFu + ((u >> 16) & 1u)) >> 16);
}
__device__ inline double shfl_down_dbl(double x, int off) {
    long long l = __double_as_longlong(x);
    int lo = (int)(l & 0xffffffffll), hi = (int)(l >> 32);
    lo = __shfl_down(lo, off); hi = __shfl_down(hi, off);
    return __longlong_as_double(((long long)hi << 32) | (unsigned long long)(unsigned int)lo);
}

// ---------------- 1a. text pooling: partial sums over t-chunks ----------------
__global__ __launch_bounds__(256) void pool_t_part_kernel(const float* __restrict__ t_pad,
                                                          const float* __restrict__ t_mask,
                                                          float* __restrict__ part) {
    __shared__ float m_s[TCH];
    const int b   = blockIdx.x;
    const int tc  = blockIdx.y;
    const int tid = threadIdx.x;
    const int t0  = tc * TCH;
    if (tid < TCH) m_s[tid] = t_mask[(size_t)b * TT + t0 + tid];
    __syncthreads();
    if (tid == 0) {
        float s = 0.f;
        for (int i = 0; i < TCH; ++i) s += m_s[i];
        part[PT_DEN + (size_t)b * TC + tc] = s;
    }
    const float* tp = t_pad + ((size_t)b * TT + t0) * DD + tid * 4;
    float4 acc = make_float4(0.f, 0.f, 0.f, 0.f);
#pragma unroll 4
    for (int t = 0; t < TCH; ++t) {
        const float4 v = *(const float4*)(tp + (size_t)t * DD);
        const float m = m_s[t];
        acc.x = fmaf(m, v.x, acc.x); acc.y = fmaf(m, v.y, acc.y);
        acc.z = fmaf(m, v.z, acc.z); acc.w = fmaf(m, v.w, acc.w);
    }
    *(float4*)(part + PT_NUM + ((size_t)b * TC + tc) * DD + tid * 4) = acc;
}

// ---------------- 2a. gaussian view pooling: partial sums ----------------
__global__ __launch_bounds__(256) void pool_v_part_kernel(const float* __restrict__ v_pad,
                                                          const float* __restrict__ centers,
                                                          const int* __restrict__ grid_thws,
                                                          float* __restrict__ part) {
    __shared__ float m_s[LCH][KV];   // 4 KB
    const int b   = blockIdx.x;
    const int lc  = blockIdx.y;
    const int tid = threadIdx.x;
    const int H = grid_thws[1];
    const int W = grid_thws[2];
    int L = H * W; if (L > LMAX) L = LMAX;
    const int l0 = lc * LCH;

    for (int i = tid; i < LCH * KV; i += 256) {
        const int ll = i >> 3, k = i & 7;
        const int l  = l0 + ll;
        float m = 0.f;
        if (l < L) {
            const int iy = l / W, ix = l - iy * W;
            const float gx = (ix + 0.5f) / (float)W;
            const float gy = (iy + 0.5f) / (float)H;
            const float dx = centers[((size_t)b * KV + k) * 2 + 0] - gx;
            const float dy = centers[((size_t)b * KV + k) * 2 + 1] - gy;
            m = expf(-10.f * (dx * dx + dy * dy));
        }
        m_s[ll][k] = m;
    }
    __syncthreads();
    if (tid < KV) {
        float s = 0.f;
        for (int ll = 0; ll < LCH; ++ll) s += m_s[ll][tid];
        part[PV_DEN + ((size_t)b * LC + lc) * KV + tid] = s;
    }

    const float* vp = v_pad + ((size_t)b * LMAX + l0) * DD + tid * 4;
    float4 acc[KV];
#pragma unroll
    for (int k = 0; k < KV; ++k) acc[k] = make_float4(0.f, 0.f, 0.f, 0.f);
#pragma unroll 4
    for (int ll = 0; ll < LCH; ++ll) {
        const float4 v = *(const float4*)(vp + (size_t)ll * DD);
#pragma unroll
        for (int k = 0; k < KV; ++k) {
            const float m = m_s[ll][k];
            acc[k].x = fmaf(m, v.x, acc[k].x); acc[k].y = fmaf(m, v.y, acc[k].y);
            acc[k].z = fmaf(m, v.z, acc[k].z); acc[k].w = fmaf(m, v.w, acc[k].w);
        }
    }
#pragma unroll
    for (int k = 0; k < KV; ++k)
        *(float4*)(part + PV_NUM + (((size_t)b * LC + lc) * KV + k) * DD + tid * 4) = acc[k];
}

// ---------------- shared epilogue helper: normalize + bf16 hi/lo planes ----------------
__device__ inline void comb_norm_emit(float4 vv, int r, int tid,
                                      float* __restrict__ out_row,      // out (pooled)
                                      float* __restrict__ ws, size_t xn_off,
                                      size_t hi_off, size_t lo_off) {
    *(float4*)(out_row + tid * 4) = vv;
    float ss = vv.x * vv.x + vv.y * vv.y + vv.z * vv.z + vv.w * vv.w;
#pragma unroll
    for (int off = 32; off; off >>= 1) ss += __shfl_down(ss, off);
    __shared__ float wsum[4];
    if ((tid & 63) == 0) wsum[tid >> 6] = ss;
    __syncthreads();
    const float tot = wsum[0] + wsum[1] + wsum[2] + wsum[3];
    const float scale = 1.f / fmaxf(sqrtf(tot), 1e-12f);
    float4 xn;
    xn.x = vv.x * scale; xn.y = vv.y * scale; xn.z = vv.z * scale; xn.w = vv.w * scale;
    *(float4*)(ws + xn_off + (size_t)r * DD + tid * 4) = xn;
    const float f[4] = {xn.x, xn.y, xn.z, xn.w};
    s16x4 hv, lv;
#pragma unroll
    for (int c = 0; c < 4; ++c) {
        const unsigned short hb = f2bf_rn(f[c]);
        const float hf = __uint_as_float((unsigned)hb << 16);
        hv[c] = (short)hb;
        lv[c] = (short)f2bf_rn(f[c] - hf);
    }
    *(s16x4*)((short*)(ws + hi_off) + (size_t)r * DD + tid * 4) = hv;
    *(s16x4*)((short*)(ws + lo_off) + (size_t)r * DD + tid * 4) = lv;
}

// ---------------- 1b. text pooling: combine + normalize + planes ----------------
__global__ __launch_bounds__(256) void pool_t_comb_kernel(const float* __restrict__ part,
                                                          float* __restrict__ out_tg,
                                                          float* __restrict__ ws) {
    const int b   = blockIdx.x;
    const int tid = threadIdx.x;
    float den = 1e-6f;
    for (int tc = 0; tc < TC; ++tc) den += part[PT_DEN + (size_t)b * TC + tc];
    float4 s = make_float4(0.f, 0.f, 0.f, 0.f);
    for (int tc = 0; tc < TC; ++tc) {
        const float4 p = *(const float4*)(part + PT_NUM + ((size_t)b * TC + tc) * DD + tid * 4);
        s.x += p.x; s.y += p.y; s.z += p.z; s.w += p.w;
    }
    const float inv = 1.f / den;
    float4 vv = make_float4(s.x * inv, s.y * inv, s.z * inv, s.w * inv);
    comb_norm_emit(vv, b, tid, out_tg + (size_t)b * DD, ws, WS_TN, WS_AHI_T, WS_ALO_T);
}

// ---------------- 2b. gaussian view pooling: combine + normalize + planes ----------------
__global__ __launch_bounds__(256) void pool_v_comb_kernel(const float* __restrict__ part,
                                                          float* __restrict__ out_views,
                                                          float* __restrict__ ws) {
    const int b   = blockIdx.x;
    const int k   = blockIdx.y;
    const int tid = threadIdx.x;
    float den = 1e-6f;
    for (int lc = 0; lc < LC; ++lc) den += part[PV_DEN + ((size_t)b * LC + lc) * KV + k];
    float4 s = make_float4(0.f, 0.f, 0.f, 0.f);
    for (int lc = 0; lc < LC; ++lc) {
        const float4 p = *(const float4*)(part + PV_NUM + (((size_t)b * LC + lc) * KV + k) * DD + tid * 4);
        s.x += p.x; s.y += p.y; s.z += p.z; s.w += p.w;
    }
    const float inv = 1.f / den;
    float4 vv = make_float4(s.x * inv, s.y * inv, s.z * inv, s.w * inv);
    const int r = b * KV + k;
    comb_norm_emit(vv, r, tid, out_views + (size_t)r * DD, ws, WS_VN, WS_AHI_V, WS_ALO_V);
}

// ---------------- 4. split-bf16 MFMA GEMM -> acts (fused enc-norm) ----------------
// C[m,h] = acts(clip((x_n[m,:].enc[h,:]) * binv[h]))
// x = hi + lo (two bf16); x.y ~= hi.hi + hi.lo + lo.hi  (3 MFMA passes)
// grid (HSAE/128, 5): y=0..3 -> vision m-tiles, y=4 -> text.
constexpr int GBM = 128, GBN = 128, GBK = 64;

// fragment-ordered LDS offset (in shorts), with XOR swizzle on the row16 slot
__device__ inline int fragoff(int sub, int g, int r16) {
    return (((sub * 8 + g) * 16) + (r16 ^ ((g & 7) << 1))) * 8;
}

__global__ __launch_bounds__(256) void gemm_acts_mfma(const float* __restrict__ encV,
                                                      const float* __restrict__ encT,
                                                      float* __restrict__ out,
                                                      float* __restrict__ ws) {
    __shared__ short Ah[GBM * GBK], Al[GBM * GBK];   // 16 KB each
    __shared__ short Bh[GBN * GBK], Bl[GBN * GBK];   // 16 KB each
    __shared__ float bn_part[GBN][8];                // 4 KB
    __shared__ float binv_s[GBN];

    const int tid  = threadIdx.x;
    const int lane = tid & 63;
    const int wv   = tid >> 6;       // 0..3
    const int wm   = wv & 1;         // wave m-tile (64 rows)
    const int wn   = wv >> 1;        // wave n-tile (64 cols)
    const int by   = blockIdx.y;
    const bool isT = (by == 4);
    const int h0   = blockIdx.x * GBN;
    const int m0   = isT ? 0 : by * GBM;
    const int M    = isT ? NROW_T : NROW_V;
    const float* Bm = isT ? encT : encV;
    const short* AhiP = (const short*)(ws + (isT ? WS_AHI_T : WS_AHI_V));
    const short* AloP = (const short*)(ws + (isT ? WS_ALO_T : WS_ALO_V));
    float* outActs = out + (isT ? OUT_LAT_T : OUT_LAT_V);
    float* binv_g  = ws + (isT ? WS_BINV_T : WS_BINV_V);

    f32x4 acc[4][4];
#pragma unroll
    for (int mi = 0; mi < 4; ++mi)
#pragma unroll
        for (int ni = 0; ni < 4; ++ni) acc[mi][ni] = (f32x4){0.f, 0.f, 0.f, 0.f};
    float bnacc[4] = {0.f, 0.f, 0.f, 0.f};

    for (int kt = 0; kt < DD; kt += GBK) {
        __syncthreads();
        // stage: 2048 (row,kslot) tasks, 8 per thread.
        // rt<4 => A rows (pure copy from preconverted planes); rt>=4 => B rows (convert + bn).
#pragma unroll
        for (int rt = 0; rt < 8; ++rt) {
            const int task = rt * 256 + tid;
            const int ks   = task & 7;
            if (rt < 4) {
                const int lr = task >> 3;           // 0..127
                bf16x8 hv = {0, 0, 0, 0, 0, 0, 0, 0};
                bf16x8 lv = {0, 0, 0, 0, 0, 0, 0, 0};
                if (m0 + lr < M) {
                    const size_t po = (size_t)(m0 + lr) * DD + kt + ks * 8;
                    hv = *(const bf16x8*)&AhiP[po];
                    lv = *(const bf16x8*)&AloP[po];
                }
                const int off = fragoff(lr >> 4, ks, lr & 15);
                *(bf16x8*)&Ah[off] = hv; *(bf16x8*)&Al[off] = lv;
            } else {
                const int lr = (task >> 3) - GBM;   // 0..127
                const float* src = Bm + (size_t)(h0 + lr) * DD + kt + ks * 8;
                const float4 v0 = *(const float4*)src;
                const float4 v1 = *(const float4*)(src + 4);
                const float f[8] = {v0.x, v0.y, v0.z, v0.w, v1.x, v1.y, v1.z, v1.w};
                bf16x8 hv, lv;
                float bsum = 0.f;
#pragma unroll
                for (int j = 0; j < 8; ++j) {
                    const unsigned short hb = f2bf_rn(f[j]);
                    const float hf = __uint_as_float((unsigned)hb << 16);
                    hv[j] = (short)hb;
                    lv[j] = (short)f2bf_rn(f[j] - hf);
                    bsum = fmaf(f[j], f[j], bsum);
                }
                bnacc[rt - 4] += bsum;
                const int off = fragoff(lr >> 4, ks, lr & 15);
                *(bf16x8*)&Bh[off] = hv; *(bf16x8*)&Bl[off] = lv;
            }
        }
        __syncthreads();

#pragma unroll
        for (int s = 0; s < 2; ++s) {      // two K=32 sub-steps per BK=64
            bf16x8 ah[4], al[4], bh[4], bl[4];
            const int g = s * 4 + (lane >> 4);
            const int r16 = lane & 15;
#pragma unroll
            for (int t = 0; t < 4; ++t) {
                const int ao = fragoff(wm * 4 + t, g, r16);
                ah[t] = *(const bf16x8*)&Ah[ao];
                al[t] = *(const bf16x8*)&Al[ao];
                const int bo = fragoff(wn * 4 + t, g, r16);
                bh[t] = *(const bf16x8*)&Bh[bo];
                bl[t] = *(const bf16x8*)&Bl[bo];
            }
#pragma unroll
            for (int mi = 0; mi < 4; ++mi)
#pragma unroll
                for (int ni = 0; ni < 4; ++ni) {
                    acc[mi][ni] = __builtin_amdgcn_mfma_f32_16x16x32_bf16(ah[mi], bh[ni], acc[mi][ni], 0, 0, 0);
                    acc[mi][ni] = __builtin_amdgcn_mfma_f32_16x16x32_bf16(ah[mi], bl[ni], acc[mi][ni], 0, 0, 0);
                    acc[mi][ni] = __builtin_amdgcn_mfma_f32_16x16x32_bf16(al[mi], bh[ni], acc[mi][ni], 0, 0, 0);
                }
        }
    }

    // enc row norms from fused sumsq: bn_part[row][ks] -> binv_s
#pragma unroll
    for (int rt = 4; rt < 8; ++rt) {
        const int task = rt * 256 + tid;
        bn_part[(task >> 3) - GBM][task & 7] = bnacc[rt - 4];
    }
    __syncthreads();
    if (tid < GBN) {
        float s = 0.f;
#pragma unroll
        for (int i = 0; i < 8; ++i) s += bn_part[tid][i];
        const float bi = 1.f / fmaxf(sqrtf(s), 1e-12f);
        binv_s[tid] = bi;
        if (by == 0 || by == 4) binv_g[h0 + tid] = bi;   // persist for topk's f64 re-rank
    }
    __syncthreads();

    // epilogue: scale by binv, clip, acts transform, store f32
#pragma unroll
    for (int mi = 0; mi < 4; ++mi)
#pragma unroll
        for (int ni = 0; ni < 4; ++ni) {
            const int hl = wn * 64 + ni * 16 + (lane & 15);
            const float bi = binv_s[hl];
#pragma unroll
            for (int j = 0; j < 4; ++j) {
                const int m = m0 + wm * 64 + mi * 16 + (lane >> 4) * 4 + j;
                if (m < M) {
                    float c = acc[mi][ni][j] * bi;
                    c = fminf(1.f, fmaxf(-1.f, c));
                    outActs[(size_t)m * HSAE + h0 + hl] = 2.f - sqrtf(fmaxf(0.f, 2.f - 2.f * c));
                }
            }
        }
}

// ---------------- 5. top-32: two-level histogram screen + exact boundary re-rank ----------------
constexpr int NBINS = 2048;
constexpr int NFINE = 256;
constexpr int CAP   = 512;
constexpr float RANKEPS = 4e-6f;   // ~9 sigma of split-bf16 GEMM acts error

__global__ __launch_bounds__(256) void topk_kernel(float* __restrict__ out_buf,
                                                   float* __restrict__ ws,
                                                   const float* __restrict__ enc_v,
                                                   const float* __restrict__ enc_t) {
    const int r    = blockIdx.x;
    const int tid  = threadIdx.x;
    const int wv   = tid >> 6;
    const int lane = tid & 63;
    float* row;
    int* idxp; float* valp;
    const float* xn; const float* enc; const float* binv;
    if (r < NROW_V) {
        row  = out_buf + OUT_LAT_V + (size_t)r * HSAE;
        idxp = (int*)(ws + WS_IDX_V) + (size_t)r * TOPK;
        valp = ws + WS_VAL_V + (size_t)r * TOPK;
        xn   = ws + WS_VN + (size_t)r * DD;
        enc  = enc_v; binv = ws + WS_BINV_V;
    } else {
        const int rr = r - NROW_V;
        row  = out_buf + OUT_LAT_T + (size_t)rr * HSAE;
        idxp = (int*)(ws + WS_IDX_T) + (size_t)rr * TOPK;
        valp = ws + WS_VAL_T + (size_t)rr * TOPK;
        xn   = ws + WS_TN + (size_t)rr * DD;
        enc  = enc_t; binv = ws + WS_BINV_T;
    }

    __shared__ unsigned int hist[4][NBINS];       // 32 KB
    __shared__ unsigned int fine[4][NFINE];       // 4 KB
    __shared__ float xs[DD];                      // 4 KB
    __shared__ unsigned long long cand[CAP];      // 4 KB
    __shared__ unsigned long long ord[CAP];       // 4 KB
    __shared__ double bval[64];
    __shared__ int    bidx[64];
    __shared__ int s_ncand, s_bin, s_cntgt, s_sub, s_A, s_E;

    for (int i = tid; i < 4 * NBINS; i += 256) ((unsigned int*)hist)[i] = 0u;
    for (int i = tid; i < 4 * NFINE; i += 256) ((unsigned int*)fine)[i] = 0u;
    if (tid == 0) { s_ncand = 0; }
    *(float4*)&xs[tid * 4] = *(const float4*)&xn[tid * 4];

    unsigned int bcache[64];
#pragma unroll
    for (int e = 0; e < 16; ++e) {
        const float4 v = *(const float4*)(row + (size_t)e * 1024 + tid * 4);
        bcache[e * 4 + 0] = __float_as_uint(v.x);
        bcache[e * 4 + 1] = __float_as_uint(v.y);
        bcache[e * 4 + 2] = __float_as_uint(v.z);
        bcache[e * 4 + 3] = __float_as_uint(v.w);
    }
#pragma unroll
    for (int e = 0; e < 16; ++e)
        *(float4*)(row + (size_t)e * 1024 + tid * 4) = make_float4(0.f, 0.f, 0.f, 0.f);
    __syncthreads();

    // ---- coarse histogram ----
#pragma unroll
    for (int e = 0; e < 64; ++e) {
        unsigned int bin = bcache[e] >> 19;
        if (bin > NBINS - 1) bin = NBINS - 1;
        atomicAdd(&hist[wv][bin], 1u);
    }
    __syncthreads();
    for (int i = tid; i < NBINS; i += 256)
        hist[0][i] += hist[1][i] + hist[2][i] + hist[3][i];
    __syncthreads();

    // ---- coarse boundary bin B0 + count strictly above it ----
    if (tid < 64) {
        unsigned int csum = 0;
#pragma unroll
        for (int j = 0; j < 32; ++j)
            csum += hist[0][tid * 32 + ((tid + j) & 31)];
        unsigned int suf = csum;
#pragma unroll
        for (int off = 1; off < 64; off <<= 1) {
            unsigned int o = __shfl_down(suf, off);
            suf += (tid + off < 64) ? o : 0u;
        }
        if (suf >= (unsigned)TOPK && (suf - csum) < (unsigned)TOPK) {
            unsigned int run = suf - csum;
            int b = tid * 32 + 31;
            for (; b > tid * 32; --b) {
                const unsigned int h = hist[0][b];
                if (run + h >= (unsigned)TOPK) break;
                run += h;
            }
            s_bin = b; s_cntgt = (int)run;
        }
    }
    __syncthreads();
    const unsigned int B0 = (unsigned int)s_bin;
    const int cnt_gt = s_cntgt;            // 0 <= cnt_gt < 32
    const int r0 = TOPK - cnt_gt;          // local rank needed inside B0

    // ---- fine histogram over B0's elements ----
#pragma unroll
    for (int e = 0; e < 64; ++e) {
        const unsigned int bits = bcache[e];
        unsigned int bin = bits >> 19;
        if (bin > NBINS - 1) bin = NBINS - 1;
        if (bin == B0) atomicAdd(&fine[wv][(bits >> 11) & 255u], 1u);
    }
    __syncthreads();
    for (int i = tid; i < NFINE; i += 256)
        fine[0][i] += fine[1][i] + fine[2][i] + fine[3][i];
    __syncthreads();

    // ---- fine boundary sub-bin S0 (contains local rank r0) ----
    if (tid < 64) {
        unsigned int csum = fine[0][tid * 4] + fine[0][tid * 4 + 1] +
                            fine[0][tid * 4 + 2] + fine[0][tid * 4 + 3];
        unsigned int suf = csum;
#pragma unroll
        for (int off = 1; off < 64; off <<= 1) {
            unsigned int o = __shfl_down(suf, off);
            suf += (tid + off < 64) ? o : 0u;
        }
        if (suf >= (unsigned)r0 && (suf - csum) < (unsigned)r0) {
            unsigned int run = suf - csum;
            int b = tid * 4 + 3;
            for (; b > tid * 4; --b) {
                const unsigned int h = fine[0][b];
                if (run + h >= (unsigned)r0) break;
                run += h;
            }
            s_sub = b;
        }
    }
    __syncthreads();
    const unsigned int S0m = (s_sub > 0) ? (unsigned)(s_sub - 1) : 0u;  // one FINE bin margin

    // ---- compact candidates: (bin > B0) || (bin == B0 && sub >= S0m) ----
#pragma unroll
    for (int e = 0; e < 64; ++e) {
        const unsigned int bits = bcache[e];
        unsigned int bin = bits >> 19;
        if (bin > NBINS - 1) bin = NBINS - 1;
        if (bin > B0 || (bin == B0 && ((bits >> 11) & 255u) >= S0m)) {
            const int slot = atomicAdd(&s_ncand, 1);
            if (slot < CAP) {
                const unsigned int idx = (unsigned)(e >> 2) * 1024u + (unsigned)tid * 4u + (unsigned)(e & 3);
                cand[slot] = ((unsigned long long)bits << 32) | (unsigned long long)(16383u - idx);
            }
        }
    }
    __syncthreads();
    const int nc = (s_ncand < CAP) ? s_ncand : CAP;

    // exact rank among candidates by GEMM value (unique keys) -> ordered list
    for (int i = tid; i < nc; i += 256) {
        const unsigned long long K = cand[i];
        int rank = 0;
        for (int j = 0; j < nc; ++j) rank += (cand[j] > K) ? 1 : 0;
        ord[rank] = K;
    }
    if (tid == 0) { s_A = nc; s_E = nc; }
    __syncthreads();

    const float Tv = __uint_as_float((unsigned)(ord[31] >> 32));  // 32nd GEMM value
    for (int i = tid; i < nc; i += 256) {
        const float v = __uint_as_float((unsigned)(ord[i] >> 32));
        if (v <= Tv + RANKEPS) atomicMin(&s_A, i);   // first possibly-ambiguous
        if (v <  Tv - RANKEPS) atomicMin(&s_E, i);   // first certainly-out
    }
    __syncthreads();
    const int A = s_A;                         // ranks [0,A): certainly in (A<=31)
    int E = s_E; if (E > A + 64) E = A + 64;   // band ranks [A,E)
    const int nb = E - A;

    // f64 recompute of the ambiguous band (typically 1-3 elements)
    for (int t = A + wv; t < E; t += 4) {
        const int idx = 16383 - (int)(ord[t] & 0xffffffffull);
        const float* er = enc + (size_t)idx * DD;
        double s = 0.0;
#pragma unroll
        for (int i = 0; i < 16; ++i) {
            const int j = lane + i * 64;
            s = fma((double)xs[j], (double)er[j], s);
        }
#pragma unroll
        for (int off = 32; off; off >>= 1) s += shfl_down_dbl(s, off);
        if (lane == 0) {
            double c = s * (double)binv[idx];
            c = fmin(1.0, fmax(-1.0, c));
            bval[t - A] = 2.0 - sqrt(fmax(0.0, 2.0 - 2.0 * c));
            bidx[t - A] = idx;
        }
    }
    __syncthreads();

    // emit certain winners (ranks [0,A))
    for (int i = tid; i < A; i += 256) {
        const int idx  = 16383 - (int)(ord[i] & 0xffffffffull);
        const float v  = __uint_as_float((unsigned)(ord[i] >> 32));
        idxp[i] = idx; valp[i] = v; row[idx] = v;
    }
    // emit band winners by exact f64 order (slots [A,32))
    for (int t = tid; t < nb; t += 256) {
        int fr = 0;
        for (int u = 0; u < nb; ++u)
            if (bval[u] > bval[t] || (bval[u] == bval[t] && bidx[u] < bidx[t])) fr++;
        const int slot = A + fr;
        if (slot < TOPK) {
            const float v = (float)bval[t];
            idxp[slot] = bidx[t]; valp[slot] = v; row[bidx[t]] = v;
        }
    }
}

// ---------------- 6. sparse reconstruction ----------------
__global__ __launch_bounds__(256) void recon_kernel(const float* __restrict__ decw,  // [D, HSAE]
                                                    const float* __restrict__ decb,  // [D]
                                                    const int* __restrict__ idxp,    // [M, 32]
                                                    const float* __restrict__ valp,  // [M, 32]
                                                    float* __restrict__ outp,        // [M, D]
                                                    int M) {
    __shared__ float wrow[HSAE];  // 64 KB
    const int d   = blockIdx.x;
    const int tid = threadIdx.x;
    const float* wr = decw + (size_t)d * HSAE;
    for (int e = 0; e < HSAE / (256 * 4); ++e)
        *(float4*)&wrow[(size_t)(e * 256 + tid) * 4] = *(const float4*)(wr + (size_t)(e * 256 + tid) * 4);
    __syncthreads();
    const float bias = decb[d];
    for (int n = tid; n < M; n += 256) {
        float acc = bias;
#pragma unroll
        for (int k = 0; k < TOPK; ++k)
            acc = fmaf(valp[n * TOPK + k], wrow[idxp[n * TOPK + k]], acc);
        outp[(size_t)n * DD + d] = acc;
    }
}

// ---------------- launch ----------------
extern "C" void kernel_launch(void* const* d_in, const int* in_sizes, int n_in,
                              void* d_out, int out_size, void* d_ws, size_t ws_size,
                              hipStream_t stream) {
    const float* v_pad    = (const float*)d_in[0];
    // d_in[1] v_len: unused by the reference
    const int*   grid_thws = (const int*)d_in[2];
    const float* t_pad    = (const float*)d_in[3];
    const float* t_mask   = (const float*)d_in[4];
    const float* centers  = (const float*)d_in[5];
    const float* enc_v    = (const float*)d_in[6];
    const float* dec_v_w  = (const float*)d_in[7];
    const float* dec_v_b  = (const float*)d_in[8];
    const float* enc_t    = (const float*)d_in[9];
    const float* dec_t_w  = (const float*)d_in[10];
    const float* dec_t_b  = (const float*)d_in[11];
    float* out = (float*)d_out;
    float* ws  = (float*)d_ws;

    pool_t_part_kernel<<<dim3(NB, TC), 256, 0, stream>>>(t_pad, t_mask, out + OUT_LAT_T);
    pool_t_comb_kernel<<<NB, 256, 0, stream>>>(out + OUT_LAT_T, out + OUT_TGLOBAL, ws);
    pool_v_part_kernel<<<dim3(NB, LC), 256, 0, stream>>>(v_pad, centers, grid_thws, out + OUT_LAT_V);
    pool_v_comb_kernel<<<dim3(NB, KV), 256, 0, stream>>>(out + OUT_LAT_V, out + OUT_VVIEWS, ws);
    gemm_acts_mfma<<<dim3(HSAE / GBN, 5), 256, 0, stream>>>(enc_v, enc_t, out, ws);
    topk_kernel<<<NROW_V + NROW_T, 256, 0, stream>>>(out, ws, enc_v, enc_t);
    recon_kernel<<<DD, 256, 0, stream>>>(dec_v_w, dec_v_b, (const int*)(ws + WS_IDX_V), ws + WS_VAL_V,
                                         out + OUT_RECON_V, NROW_V);
    recon_kernel<<<DD, 256, 0, stream>>>(dec_t_w, dec_t_b, (const int*)(ws + WS_IDX_T), ws + WS_VAL_T,
                                         out + OUT_RECON_T, NROW_T);
}

// Round 7
// 335.835 us; speedup vs baseline: 4.2553x; 1.1565x over previous
//
#include <hip/hip_runtime.h>
#include <hip/hip_bf16.h>

// ---------------- problem constants (fixed by setup_inputs) ----------------
constexpr int NB    = 64;      // batch
constexpr int LMAX  = 1024;    // max vision tokens
constexpr int DD    = 1024;    // feature dim
constexpr int HSAE  = 16384;   // SAE latent dim
constexpr int TT    = 512;     // text tokens
constexpr int KV    = 8;       // views per batch
constexpr int TOPK  = 32;
constexpr int NROW_V = NB * KV;   // 512
constexpr int NROW_T = NB;        // 64

// output offsets (floats), concatenated in reference return order
constexpr size_t OUT_RECON_V = 0;                                   // [512,1024]
constexpr size_t OUT_VVIEWS  = OUT_RECON_V + (size_t)NROW_V * DD;   // [512,1024]
constexpr size_t OUT_RECON_T = OUT_VVIEWS + (size_t)NROW_V * DD;    // [64,1024]
constexpr size_t OUT_TGLOBAL = OUT_RECON_T + (size_t)NROW_T * DD;   // [64,1024]
constexpr size_t OUT_LAT_V   = OUT_TGLOBAL + (size_t)NROW_T * DD;   // [512,16384]
constexpr size_t OUT_LAT_T   = OUT_LAT_V + (size_t)NROW_V * HSAE;   // [64,16384]

// workspace offsets (floats)
constexpr size_t WS_VN     = 0;                                   // x_n views [512,1024]
constexpr size_t WS_TN     = WS_VN + (size_t)NROW_V * DD;         // x_n text  [64,1024]
constexpr size_t WS_IDX_V  = WS_TN + (size_t)NROW_T * DD;         // int [512,32]
constexpr size_t WS_VAL_V  = WS_IDX_V + (size_t)NROW_V * TOPK;    // f32 [512,32]
constexpr size_t WS_IDX_T  = WS_VAL_V + (size_t)NROW_V * TOPK;    // int [64,32]
constexpr size_t WS_VAL_T  = WS_IDX_T + (size_t)NROW_T * TOPK;    // f32 [64,32]
constexpr size_t WS_BINV_V = WS_VAL_T + (size_t)NROW_T * TOPK;    // f32 [16384]
constexpr size_t WS_BINV_T = WS_BINV_V + (size_t)HSAE;            // f32 [16384]
// pre-converted x_n hi bf16 plane (linear [row][k], shorts) — hi only (2-pass GEMM)
constexpr size_t WS_AHI_V  = WS_BINV_T + (size_t)HSAE;                 // 512*1024 shorts
constexpr size_t WS_AHI_T  = WS_AHI_V + (size_t)NROW_V * DD / 2;       // 64*1024 shorts

// pooling partial-sum scratch inside the (not-yet-written) latent regions
constexpr int LC  = 8;             // l-chunks for vision pooling
constexpr int LCH = LMAX / LC;     // 128
constexpr int TC  = 8;             // t-chunks for text pooling
constexpr int TCH = TT / TC;       // 64
constexpr size_t PV_NUM = 0;                                  // [NB*LC][KV][DD]
constexpr size_t PV_DEN = (size_t)NB * LC * KV * DD;          // [NB*LC][KV]
constexpr size_t PT_NUM = 0;                                  // [NB*TC][DD]
constexpr size_t PT_DEN = (size_t)NB * TC * DD;               // [NB*TC]

typedef __attribute__((ext_vector_type(8))) short bf16x8;
typedef __attribute__((ext_vector_type(4))) short s16x4;
typedef __attribute__((ext_vector_type(4))) float f32x4;

__device__ inline unsigned short f2bf_rn(float x) {
    unsigned u = __float_as_uint(x);
    return (unsigned short)((u + 0x7FFFu + ((u >> 16) & 1u)) >> 16);
}
__device__ inline double shfl_down_dbl(double x, int off) {
    long long l = __double_as_longlong(x);
    int lo = (int)(l & 0xffffffffll), hi = (int)(l >> 32);
    lo = __shfl_down(lo, off); hi = __shfl_down(hi, off);
    return __longlong_as_double(((long long)hi << 32) | (unsigned long long)(unsigned int)lo);
}

// ---------------- 1. fused pooling partials (vision y<8, text y>=8) ----------------
__global__ __launch_bounds__(256) void pool_part_kernel(const float* __restrict__ v_pad,
                                                        const float* __restrict__ centers,
                                                        const int* __restrict__ grid_thws,
                                                        const float* __restrict__ t_pad,
                                                        const float* __restrict__ t_mask,
                                                        float* __restrict__ partV,
                                                        float* __restrict__ partT) {
    __shared__ float m_s[LCH * KV];   // 4 KB (text uses first TCH floats)
    const int b   = blockIdx.x;
    const int tid = threadIdx.x;

    if (blockIdx.y < LC) {
        // ---- vision chunk ----
        const int lc = blockIdx.y;
        const int H = grid_thws[1];
        const int W = grid_thws[2];
        int L = H * W; if (L > LMAX) L = LMAX;
        const int l0 = lc * LCH;

        for (int i = tid; i < LCH * KV; i += 256) {
            const int ll = i >> 3, k = i & 7;
            const int l  = l0 + ll;
            float m = 0.f;
            if (l < L) {
                const int iy = l / W, ix = l - iy * W;
                const float gx = (ix + 0.5f) / (float)W;
                const float gy = (iy + 0.5f) / (float)H;
                const float dx = centers[((size_t)b * KV + k) * 2 + 0] - gx;
                const float dy = centers[((size_t)b * KV + k) * 2 + 1] - gy;
                m = expf(-10.f * (dx * dx + dy * dy));
            }
            m_s[ll * KV + k] = m;
        }
        __syncthreads();
        if (tid < KV) {
            float s = 0.f;
            for (int ll = 0; ll < LCH; ++ll) s += m_s[ll * KV + tid];
            partV[PV_DEN + ((size_t)b * LC + lc) * KV + tid] = s;
        }

        const float* vp = v_pad + ((size_t)b * LMAX + l0) * DD + tid * 4;
        float4 acc[KV];
#pragma unroll
        for (int k = 0; k < KV; ++k) acc[k] = make_float4(0.f, 0.f, 0.f, 0.f);
#pragma unroll 4
        for (int ll = 0; ll < LCH; ++ll) {
            const float4 v = *(const float4*)(vp + (size_t)ll * DD);
#pragma unroll
            for (int k = 0; k < KV; ++k) {
                const float m = m_s[ll * KV + k];
                acc[k].x = fmaf(m, v.x, acc[k].x); acc[k].y = fmaf(m, v.y, acc[k].y);
                acc[k].z = fmaf(m, v.z, acc[k].z); acc[k].w = fmaf(m, v.w, acc[k].w);
            }
        }
#pragma unroll
        for (int k = 0; k < KV; ++k)
            *(float4*)(partV + PV_NUM + (((size_t)b * LC + lc) * KV + k) * DD + tid * 4) = acc[k];
    } else {
        // ---- text chunk ----
        const int tc = blockIdx.y - LC;
        const int t0 = tc * TCH;
        if (tid < TCH) m_s[tid] = t_mask[(size_t)b * TT + t0 + tid];
        __syncthreads();
        if (tid == 0) {
            float s = 0.f;
            for (int i = 0; i < TCH; ++i) s += m_s[i];
            partT[PT_DEN + (size_t)b * TC + tc] = s;
        }
        const float* tp = t_pad + ((size_t)b * TT + t0) * DD + tid * 4;
        float4 acc = make_float4(0.f, 0.f, 0.f, 0.f);
#pragma unroll 4
        for (int t = 0; t < TCH; ++t) {
            const float4 v = *(const float4*)(tp + (size_t)t * DD);
            const float m = m_s[t];
            acc.x = fmaf(m, v.x, acc.x); acc.y = fmaf(m, v.y, acc.y);
            acc.z = fmaf(m, v.z, acc.z); acc.w = fmaf(m, v.w, acc.w);
        }
        *(float4*)(partT + PT_NUM + ((size_t)b * TC + tc) * DD + tid * 4) = acc;
    }
}

// ---------------- 2. fused combine + normalize + hi-plane ----------------
__device__ inline void comb_norm_emit(float4 vv, int r, int tid,
                                      float* __restrict__ out_row,
                                      float* __restrict__ ws, size_t xn_off, size_t hi_off) {
    *(float4*)(out_row + tid * 4) = vv;
    float ss = vv.x * vv.x + vv.y * vv.y + vv.z * vv.z + vv.w * vv.w;
#pragma unroll
    for (int off = 32; off; off >>= 1) ss += __shfl_down(ss, off);
    __shared__ float wsum[4];
    if ((tid & 63) == 0) wsum[tid >> 6] = ss;
    __syncthreads();
    const float tot = wsum[0] + wsum[1] + wsum[2] + wsum[3];
    const float scale = 1.f / fmaxf(sqrtf(tot), 1e-12f);
    float4 xn;
    xn.x = vv.x * scale; xn.y = vv.y * scale; xn.z = vv.z * scale; xn.w = vv.w * scale;
    *(float4*)(ws + xn_off + (size_t)r * DD + tid * 4) = xn;
    const float f[4] = {xn.x, xn.y, xn.z, xn.w};
    s16x4 hv;
#pragma unroll
    for (int c = 0; c < 4; ++c) hv[c] = (short)f2bf_rn(f[c]);
    *(s16x4*)((short*)(ws + hi_off) + (size_t)r * DD + tid * 4) = hv;
}

__global__ __launch_bounds__(256) void pool_comb_kernel(const float* __restrict__ partV,
                                                        const float* __restrict__ partT,
                                                        float* __restrict__ out_views,
                                                        float* __restrict__ out_tg,
                                                        float* __restrict__ ws) {
    const int b   = blockIdx.x;
    const int k   = blockIdx.y;       // 0..7 vision view, 8 text
    const int tid = threadIdx.x;
    if (k < KV) {
        float den = 1e-6f;
        for (int lc = 0; lc < LC; ++lc) den += partV[PV_DEN + ((size_t)b * LC + lc) * KV + k];
        float4 s = make_float4(0.f, 0.f, 0.f, 0.f);
        for (int lc = 0; lc < LC; ++lc) {
            const float4 p = *(const float4*)(partV + PV_NUM + (((size_t)b * LC + lc) * KV + k) * DD + tid * 4);
            s.x += p.x; s.y += p.y; s.z += p.z; s.w += p.w;
        }
        const float inv = 1.f / den;
        float4 vv = make_float4(s.x * inv, s.y * inv, s.z * inv, s.w * inv);
        const int r = b * KV + k;
        comb_norm_emit(vv, r, tid, out_views + (size_t)r * DD, ws, WS_VN, WS_AHI_V);
    } else {
        float den = 1e-6f;
        for (int tc = 0; tc < TC; ++tc) den += partT[PT_DEN + (size_t)b * TC + tc];
        float4 s = make_float4(0.f, 0.f, 0.f, 0.f);
        for (int tc = 0; tc < TC; ++tc) {
            const float4 p = *(const float4*)(partT + PT_NUM + ((size_t)b * TC + tc) * DD + tid * 4);
            s.x += p.x; s.y += p.y; s.z += p.z; s.w += p.w;
        }
        const float inv = 1.f / den;
        float4 vv = make_float4(s.x * inv, s.y * inv, s.z * inv, s.w * inv);
        comb_norm_emit(vv, b, tid, out_tg + (size_t)b * DD, ws, WS_TN, WS_AHI_T);
    }
}

// ---------------- 4. 2-pass split-bf16 MFMA GEMM -> acts (fused enc-norm) ----------------
// computed = hi(x) . (hi(y)+lo(y)) = hi(x).y  (error = (x-hi(x)).y, sigma ~3.5e-5)
// 1-D grid 640, XCD-grouped: all 5 m-tiles of an h-block on one XCD (enc L2 reuse).
constexpr int GBM = 128, GBN = 128, GBK = 64;

__device__ inline int fragoff(int sub, int g, int r16) {
    return (((sub * 8 + g) * 16) + (r16 ^ ((g & 7) << 1))) * 8;
}

__global__ __launch_bounds__(256) void gemm_acts_mfma(const float* __restrict__ encV,
                                                      const float* __restrict__ encT,
                                                      float* __restrict__ out,
                                                      float* __restrict__ ws) {
    __shared__ short Ah[GBM * GBK];                  // 16 KB
    __shared__ short Bh[GBN * GBK], Bl[GBN * GBK];   // 16 KB each
    __shared__ float bn_part[GBN][8];                // 4 KB
    __shared__ float binv_s[GBN];

    const int tid  = threadIdx.x;
    const int lane = tid & 63;
    const int wv   = tid >> 6;       // 0..3
    const int wm   = wv & 1;         // wave m-tile (64 rows)
    const int wn   = wv >> 1;        // wave n-tile (64 cols)
    // XCD-grouped mapping: consecutive blocks on one XCD share the enc h-tile
    const int bid  = blockIdx.x;
    const int xcd  = bid & 7;
    const int slot = bid >> 3;        // 0..79
    const int hb   = xcd + 8 * (slot / 5);   // 0..127
    const int my   = slot % 5;               // 0..3 vision m-tile, 4 text
    const bool isT = (my == 4);
    const int h0   = hb * GBN;
    const int m0   = isT ? 0 : my * GBM;
    const int M    = isT ? NROW_T : NROW_V;
    const float* Bm = isT ? encT : encV;
    const short* AhiP = (const short*)(ws + (isT ? WS_AHI_T : WS_AHI_V));
    float* outActs = out + (isT ? OUT_LAT_T : OUT_LAT_V);
    float* binv_g  = ws + (isT ? WS_BINV_T : WS_BINV_V);

    f32x4 acc[4][4];
#pragma unroll
    for (int mi = 0; mi < 4; ++mi)
#pragma unroll
        for (int ni = 0; ni < 4; ++ni) acc[mi][ni] = (f32x4){0.f, 0.f, 0.f, 0.f};
    float bnacc[4] = {0.f, 0.f, 0.f, 0.f};

    for (int kt = 0; kt < DD; kt += GBK) {
        __syncthreads();
        // stage: 2048 (row,kslot) tasks, 8 per thread.
        // rt<4 => A rows (pure bf16x8 copy from hi plane); rt>=4 => B rows (convert + bn).
#pragma unroll
        for (int rt = 0; rt < 8; ++rt) {
            const int task = rt * 256 + tid;
            const int ks   = task & 7;
            if (rt < 4) {
                const int lr = task >> 3;           // 0..127
                bf16x8 hv = {0, 0, 0, 0, 0, 0, 0, 0};
                if (m0 + lr < M)
                    hv = *(const bf16x8*)&AhiP[(size_t)(m0 + lr) * DD + kt + ks * 8];
                *(bf16x8*)&Ah[fragoff(lr >> 4, ks, lr & 15)] = hv;
            } else {
                const int lr = (task >> 3) - GBM;   // 0..127
                const float* src = Bm + (size_t)(h0 + lr) * DD + kt + ks * 8;
                const float4 v0 = *(const float4*)src;
                const float4 v1 = *(const float4*)(src + 4);
                const float f[8] = {v0.x, v0.y, v0.z, v0.w, v1.x, v1.y, v1.z, v1.w};
                bf16x8 hv, lv;
                float bsum = 0.f;
#pragma unroll
                for (int j = 0; j < 8; ++j) {
                    const unsigned short hb16 = f2bf_rn(f[j]);
                    const float hf = __uint_as_float((unsigned)hb16 << 16);
                    hv[j] = (short)hb16;
                    lv[j] = (short)f2bf_rn(f[j] - hf);
                    bsum = fmaf(f[j], f[j], bsum);
                }
                bnacc[rt - 4] += bsum;
                const int off = fragoff(lr >> 4, ks, lr & 15);
                *(bf16x8*)&Bh[off] = hv; *(bf16x8*)&Bl[off] = lv;
            }
        }
        __syncthreads();

#pragma unroll
        for (int s = 0; s < 2; ++s) {      // two K=32 sub-steps per BK=64
            bf16x8 ah[4], bh[4], bl[4];
            const int g = s * 4 + (lane >> 4);
            const int r16 = lane & 15;
#pragma unroll
            for (int t = 0; t < 4; ++t) {
                ah[t] = *(const bf16x8*)&Ah[fragoff(wm * 4 + t, g, r16)];
                const int bo = fragoff(wn * 4 + t, g, r16);
                bh[t] = *(const bf16x8*)&Bh[bo];
                bl[t] = *(const bf16x8*)&Bl[bo];
            }
#pragma unroll
            for (int mi = 0; mi < 4; ++mi)
#pragma unroll
                for (int ni = 0; ni < 4; ++ni) {
                    acc[mi][ni] = __builtin_amdgcn_mfma_f32_16x16x32_bf16(ah[mi], bh[ni], acc[mi][ni], 0, 0, 0);
                    acc[mi][ni] = __builtin_amdgcn_mfma_f32_16x16x32_bf16(ah[mi], bl[ni], acc[mi][ni], 0, 0, 0);
                }
        }
    }

    // enc row norms from fused sumsq
#pragma unroll
    for (int rt = 4; rt < 8; ++rt) {
        const int task = rt * 256 + tid;
        bn_part[(task >> 3) - GBM][task & 7] = bnacc[rt - 4];
    }
    __syncthreads();
    if (tid < GBN) {
        float s = 0.f;
#pragma unroll
        for (int i = 0; i < 8; ++i) s += bn_part[tid][i];
        const float bi = 1.f / fmaxf(sqrtf(s), 1e-12f);
        binv_s[tid] = bi;
        if (my == 0 || my == 4) binv_g[h0 + tid] = bi;   // persist for topk's f64 re-rank
    }
    __syncthreads();

    // epilogue: scale by binv, clip, acts transform, store f32
#pragma unroll
    for (int mi = 0; mi < 4; ++mi)
#pragma unroll
        for (int ni = 0; ni < 4; ++ni) {
            const int hl = wn * 64 + ni * 16 + (lane & 15);
            const float bi = binv_s[hl];
#pragma unroll
            for (int j = 0; j < 4; ++j) {
                const int m = m0 + wm * 64 + mi * 16 + (lane >> 4) * 4 + j;
                if (m < M) {
                    float c = acc[mi][ni][j] * bi;
                    c = fminf(1.f, fmaxf(-1.f, c));
                    outActs[(size_t)m * HSAE + h0 + hl] = 2.f - sqrtf(fmaxf(0.f, 2.f - 2.f * c));
                }
            }
        }
}

// ---------------- 5. top-32: histogram screen (monotone-key margin) + f64 re-rank ----------------
constexpr int NBINS = 2048;
constexpr int NFINE = 256;
constexpr int CAP   = 512;
constexpr int BANDCAP = 128;
constexpr int MARGIN  = 12;        // fine bins: 12*1.22e-4 = 1.46e-3 >= 4*RANKEPS + bin
constexpr float RANKEPS = 2.5e-4f; // ~7 sigma of 2-pass GEMM acts error

__global__ __launch_bounds__(256) void topk_kernel(float* __restrict__ out_buf,
                                                   float* __restrict__ ws,
                                                   const float* __restrict__ enc_v,
                                                   const float* __restrict__ enc_t) {
    const int r    = blockIdx.x;
    const int tid  = threadIdx.x;
    const int wv   = tid >> 6;
    const int lane = tid & 63;
    float* row;
    int* idxp; float* valp;
    const float* xn; const float* enc; const float* binv;
    if (r < NROW_V) {
        row  = out_buf + OUT_LAT_V + (size_t)r * HSAE;
        idxp = (int*)(ws + WS_IDX_V) + (size_t)r * TOPK;
        valp = ws + WS_VAL_V + (size_t)r * TOPK;
        xn   = ws + WS_VN + (size_t)r * DD;
        enc  = enc_v; binv = ws + WS_BINV_V;
    } else {
        const int rr = r - NROW_V;
        row  = out_buf + OUT_LAT_T + (size_t)rr * HSAE;
        idxp = (int*)(ws + WS_IDX_T) + (size_t)rr * TOPK;
        valp = ws + WS_VAL_T + (size_t)rr * TOPK;
        xn   = ws + WS_TN + (size_t)rr * DD;
        enc  = enc_t; binv = ws + WS_BINV_T;
    }

    __shared__ unsigned int hist[4][NBINS];       // 32 KB
    __shared__ unsigned int fine[4][NFINE];       // 4 KB
    __shared__ float xs[DD];                      // 4 KB
    __shared__ unsigned long long cand[CAP];      // 4 KB
    __shared__ unsigned long long ord[CAP];       // 4 KB
    __shared__ double bval[BANDCAP];
    __shared__ int    bidx[BANDCAP];
    __shared__ int s_ncand, s_bin, s_cntgt, s_sub, s_A, s_E;

    for (int i = tid; i < 4 * NBINS; i += 256) ((unsigned int*)hist)[i] = 0u;
    for (int i = tid; i < 4 * NFINE; i += 256) ((unsigned int*)fine)[i] = 0u;
    if (tid == 0) { s_ncand = 0; }
    *(float4*)&xs[tid * 4] = *(const float4*)&xn[tid * 4];

    unsigned int bcache[64];
#pragma unroll
    for (int e = 0; e < 16; ++e) {
        const float4 v = *(const float4*)(row + (size_t)e * 1024 + tid * 4);
        bcache[e * 4 + 0] = __float_as_uint(v.x);
        bcache[e * 4 + 1] = __float_as_uint(v.y);
        bcache[e * 4 + 2] = __float_as_uint(v.z);
        bcache[e * 4 + 3] = __float_as_uint(v.w);
    }
#pragma unroll
    for (int e = 0; e < 16; ++e)
        *(float4*)(row + (size_t)e * 1024 + tid * 4) = make_float4(0.f, 0.f, 0.f, 0.f);
    __syncthreads();

    // ---- coarse histogram ----
#pragma unroll
    for (int e = 0; e < 64; ++e) {
        unsigned int bin = bcache[e] >> 19;
        if (bin > NBINS - 1) bin = NBINS - 1;
        atomicAdd(&hist[wv][bin], 1u);
    }
    __syncthreads();
    for (int i = tid; i < NBINS; i += 256)
        hist[0][i] += hist[1][i] + hist[2][i] + hist[3][i];
    __syncthreads();

    // ---- coarse boundary bin B0 + count strictly above ----
    if (tid < 64) {
        unsigned int csum = 0;
#pragma unroll
        for (int j = 0; j < 32; ++j)
            csum += hist[0][tid * 32 + ((tid + j) & 31)];
        unsigned int suf = csum;
#pragma unroll
        for (int off = 1; off < 64; off <<= 1) {
            unsigned int o = __shfl_down(suf, off);
            suf += (tid + off < 64) ? o : 0u;
        }
        if (suf >= (unsigned)TOPK && (suf - csum) < (unsigned)TOPK) {
            unsigned int run = suf - csum;
            int b = tid * 32 + 31;
            for (; b > tid * 32; --b) {
                const unsigned int h = hist[0][b];
                if (run + h >= (unsigned)TOPK) break;
                run += h;
            }
            s_bin = b; s_cntgt = (int)run;
        }
    }
    __syncthreads();
    const unsigned int B0 = (unsigned int)s_bin;
    const int r0 = TOPK - s_cntgt;         // local rank needed inside B0

    // ---- fine histogram over B0's elements ----
#pragma unroll
    for (int e = 0; e < 64; ++e) {
        const unsigned int bits = bcache[e];
        unsigned int bin = bits >> 19;
        if (bin > NBINS - 1) bin = NBINS - 1;
        if (bin == B0) atomicAdd(&fine[wv][(bits >> 11) & 255u], 1u);
    }
    __syncthreads();
    for (int i = tid; i < NFINE; i += 256)
        fine[0][i] += fine[1][i] + fine[2][i] + fine[3][i];
    __syncthreads();

    // ---- fine boundary sub-bin S0 (contains local rank r0) ----
    if (tid < 64) {
        unsigned int csum = fine[0][tid * 4] + fine[0][tid * 4 + 1] +
                            fine[0][tid * 4 + 2] + fine[0][tid * 4 + 3];
        unsigned int suf = csum;
#pragma unroll
        for (int off = 1; off < 64; off <<= 1) {
            unsigned int o = __shfl_down(suf, off);
            suf += (tid + off < 64) ? o : 0u;
        }
        if (suf >= (unsigned)r0 && (suf - csum) < (unsigned)r0) {
            unsigned int run = suf - csum;
            int b = tid * 4 + 3;
            for (; b > tid * 4; --b) {
                const unsigned int h = fine[0][b];
                if (run + h >= (unsigned)r0) break;
                run += h;
            }
            s_sub = b;
        }
    }
    __syncthreads();
    // monotone combined key threshold: boundary cf minus MARGIN fine bins
    const unsigned int cf0 = (B0 << 8) | (unsigned)s_sub;
    const unsigned int cfTh = cf0 - (unsigned)MARGIN;   // cf0 >> MARGIN always (acts ~0.6)

    // ---- compact candidates: (bits>>11) >= cfTh ----
#pragma unroll
    for (int e = 0; e < 64; ++e) {
        const unsigned int bits = bcache[e];
        if ((bits >> 11) >= cfTh) {
            const int slot = atomicAdd(&s_ncand, 1);
            if (slot < CAP) {
                const unsigned int idx = (unsigned)(e >> 2) * 1024u + (unsigned)tid * 4u + (unsigned)(e & 3);
                cand[slot] = ((unsigned long long)bits << 32) | (unsigned long long)(16383u - idx);
            }
        }
    }
    __syncthreads();
    const int nc = (s_ncand < CAP) ? s_ncand : CAP;

    // exact rank among candidates by GEMM value (unique keys) -> ordered list
    for (int i = tid; i < nc; i += 256) {
        const unsigned long long K = cand[i];
        int rank = 0;
        for (int j = 0; j < nc; ++j) rank += (cand[j] > K) ? 1 : 0;
        ord[rank] = K;
    }
    if (tid == 0) { s_A = nc; s_E = nc; }
    __syncthreads();

    const float Tv = __uint_as_float((unsigned)(ord[31] >> 32));  // 32nd GEMM value
    for (int i = tid; i < nc; i += 256) {
        const float v = __uint_as_float((unsigned)(ord[i] >> 32));
        if (v <= Tv + 2.f * RANKEPS) atomicMin(&s_A, i);   // first possibly-ambiguous
        if (v <  Tv - 2.f * RANKEPS) atomicMin(&s_E, i);   // first certainly-out
    }
    __syncthreads();
    const int A = s_A;                                 // ranks [0,A): certainly in
    int E = s_E; if (E > A + BANDCAP) E = A + BANDCAP; // band ranks [A,E)
    const int nb = E - A;

    // f64 recompute of the ambiguous band (typically ~4-8 elements)
    for (int t = A + wv; t < E; t += 4) {
        const int idx = 16383 - (int)(ord[t] & 0xffffffffull);
        const float* er = enc + (size_t)idx * DD;
        double s = 0.0;
#pragma unroll
        for (int i = 0; i < 16; ++i) {
            const int j = lane + i * 64;
            s = fma((double)xs[j], (double)er[j], s);
        }
#pragma unroll
        for (int off = 32; off; off >>= 1) s += shfl_down_dbl(s, off);
        if (lane == 0) {
            double c = s * (double)binv[idx];
            c = fmin(1.0, fmax(-1.0, c));
            bval[t - A] = 2.0 - sqrt(fmax(0.0, 2.0 - 2.0 * c));
            bidx[t - A] = idx;
        }
    }
    __syncthreads();

    // emit certain winners (ranks [0,A))
    for (int i = tid; i < A; i += 256) {
        const int idx  = 16383 - (int)(ord[i] & 0xffffffffull);
        const float v  = __uint_as_float((unsigned)(ord[i] >> 32));
        idxp[i] = idx; valp[i] = v; row[idx] = v;
    }
    // emit band winners by exact f64 order (slots [A,32))
    for (int t = tid; t < nb; t += 256) {
        int fr = 0;
        for (int u = 0; u < nb; ++u)
            if (bval[u] > bval[t] || (bval[u] == bval[t] && bidx[u] < bidx[t])) fr++;
        const int slot = A + fr;
        if (slot < TOPK) {
            const float v = (float)bval[t];
            idxp[slot] = bidx[t]; valp[slot] = v; row[bidx[t]] = v;
        }
    }
}

// ---------------- 6. fused sparse reconstruction (V blocks 0..1023, T 1024..2047) ----------------
__global__ __launch_bounds__(256) void recon_kernel(const float* __restrict__ dvw,
                                                    const float* __restrict__ dvb,
                                                    const float* __restrict__ dtw,
                                                    const float* __restrict__ dtb,
                                                    const float* __restrict__ ws,
                                                    float* __restrict__ out) {
    __shared__ float wrow[HSAE];  // 64 KB
    const int bid = blockIdx.x;
    const bool isT = bid >= DD;
    const int d   = isT ? bid - DD : bid;
    const int tid = threadIdx.x;
    const float* decw = isT ? dtw : dvw;
    const float* decb = isT ? dtb : dvb;
    const int*   idxp = (const int*)(ws + (isT ? WS_IDX_T : WS_IDX_V));
    const float* valp = ws + (isT ? WS_VAL_T : WS_VAL_V);
    float* outp = out + (isT ? OUT_RECON_T : OUT_RECON_V);
    const int M = isT ? NROW_T : NROW_V;

    const float* wr = decw + (size_t)d * HSAE;
    for (int e = 0; e < HSAE / (256 * 4); ++e)
        *(float4*)&wrow[(size_t)(e * 256 + tid) * 4] = *(const float4*)(wr + (size_t)(e * 256 + tid) * 4);
    __syncthreads();
    const float bias = decb[d];
    for (int n = tid; n < M; n += 256) {
        float acc = bias;
#pragma unroll
        for (int k = 0; k < TOPK; ++k)
            acc = fmaf(valp[n * TOPK + k], wrow[idxp[n * TOPK + k]], acc);
        outp[(size_t)n * DD + d] = acc;
    }
}

// ---------------- launch ----------------
extern "C" void kernel_launch(void* const* d_in, const int* in_sizes, int n_in,
                              void* d_out, int out_size, void* d_ws, size_t ws_size,
                              hipStream_t stream) {
    const float* v_pad    = (const float*)d_in[0];
    // d_in[1] v_len: unused by the reference
    const int*   grid_thws = (const int*)d_in[2];
    const float* t_pad    = (const float*)d_in[3];
    const float* t_mask   = (const float*)d_in[4];
    const float* centers  = (const float*)d_in[5];
    const float* enc_v    = (const float*)d_in[6];
    const float* dec_v_w  = (const float*)d_in[7];
    const float* dec_v_b  = (const float*)d_in[8];
    const float* enc_t    = (const float*)d_in[9];
    const float* dec_t_w  = (const float*)d_in[10];
    const float* dec_t_b  = (const float*)d_in[11];
    float* out = (float*)d_out;
    float* ws  = (float*)d_ws;

    pool_part_kernel<<<dim3(NB, LC + TC), 256, 0, stream>>>(v_pad, centers, grid_thws, t_pad, t_mask,
                                                            out + OUT_LAT_V, out + OUT_LAT_T);
    pool_comb_kernel<<<dim3(NB, KV + 1), 256, 0, stream>>>(out + OUT_LAT_V, out + OUT_LAT_T,
                                                           out + OUT_VVIEWS, out + OUT_TGLOBAL, ws);
    gemm_acts_mfma<<<640, 256, 0, stream>>>(enc_v, enc_t, out, ws);
    topk_kernel<<<NROW_V + NROW_T, 256, 0, stream>>>(out, ws, enc_v, enc_t);
    recon_kernel<<<2 * DD, 256, 0, stream>>>(dec_v_w, dec_v_b, dec_t_w, dec_t_b, ws, out);
}

// Round 8
// 290.065 us; speedup vs baseline: 4.9267x; 1.1578x over previous
//
#include <hip/hip_runtime.h>
#include <hip/hip_bf16.h>

// ---------------- problem constants (fixed by setup_inputs) ----------------
constexpr int NB    = 64;      // batch
constexpr int LMAX  = 1024;    // max vision tokens
constexpr int DD    = 1024;    // feature dim
constexpr int HSAE  = 16384;   // SAE latent dim
constexpr int TT    = 512;     // text tokens
constexpr int KV    = 8;       // views per batch
constexpr int TOPK  = 32;
constexpr int NROW_V = NB * KV;   // 512
constexpr int NROW_T = NB;        // 64

// output offsets (floats), concatenated in reference return order
constexpr size_t OUT_RECON_V = 0;                                   // [512,1024]
constexpr size_t OUT_VVIEWS  = OUT_RECON_V + (size_t)NROW_V * DD;   // [512,1024]
constexpr size_t OUT_RECON_T = OUT_VVIEWS + (size_t)NROW_V * DD;    // [64,1024]
constexpr size_t OUT_TGLOBAL = OUT_RECON_T + (size_t)NROW_T * DD;   // [64,1024]
constexpr size_t OUT_LAT_V   = OUT_TGLOBAL + (size_t)NROW_T * DD;   // [512,16384]
constexpr size_t OUT_LAT_T   = OUT_LAT_V + (size_t)NROW_V * HSAE;   // [64,16384]

// workspace offsets (floats)
constexpr size_t WS_VN     = 0;                                   // x_n views [512,1024]
constexpr size_t WS_TN     = WS_VN + (size_t)NROW_V * DD;         // x_n text  [64,1024]
constexpr size_t WS_IDX_V  = WS_TN + (size_t)NROW_T * DD;         // int [512,32]
constexpr size_t WS_VAL_V  = WS_IDX_V + (size_t)NROW_V * TOPK;    // f32 [512,32]
constexpr size_t WS_IDX_T  = WS_VAL_V + (size_t)NROW_V * TOPK;    // int [64,32]
constexpr size_t WS_VAL_T  = WS_IDX_T + (size_t)NROW_T * TOPK;    // f32 [64,32]
constexpr size_t WS_BINV_V = WS_VAL_T + (size_t)NROW_T * TOPK;    // f32 [16384]
constexpr size_t WS_BINV_T = WS_BINV_V + (size_t)HSAE;            // f32 [16384]
// pre-converted x_n hi bf16 plane (linear [row][k], shorts) — hi only (2-pass GEMM)
constexpr size_t WS_AHI_V  = WS_BINV_T + (size_t)HSAE;                 // 512*1024 shorts
constexpr size_t WS_AHI_T  = WS_AHI_V + (size_t)NROW_V * DD / 2;       // 64*1024 shorts

// pooling partial-sum scratch inside the (not-yet-written) latent regions
constexpr int LC  = 8;             // l-chunks for vision pooling
constexpr int LCH = LMAX / LC;     // 128
constexpr int TC  = 8;             // t-chunks for text pooling
constexpr int TCH = TT / TC;       // 64
constexpr size_t PV_NUM = 0;                                  // [NB*LC][KV][DD]
constexpr size_t PV_DEN = (size_t)NB * LC * KV * DD;          // [NB*LC][KV]
constexpr size_t PT_NUM = 0;                                  // [NB*TC][DD]
constexpr size_t PT_DEN = (size_t)NB * TC * DD;               // [NB*TC]

typedef __attribute__((ext_vector_type(8))) short bf16x8;
typedef __attribute__((ext_vector_type(4))) short s16x4;
typedef __attribute__((ext_vector_type(4))) float f32x4;

__device__ inline unsigned short f2bf_rn(float x) {
    unsigned u = __float_as_uint(x);
    return (unsigned short)((u + 0x7FFFu + ((u >> 16) & 1u)) >> 16);
}
__device__ inline double shfl_down_dbl(double x, int off) {
    long long l = __double_as_longlong(x);
    int lo = (int)(l & 0xffffffffll), hi = (int)(l >> 32);
    lo = __shfl_down(lo, off); hi = __shfl_down(hi, off);
    return __longlong_as_double(((long long)hi << 32) | (unsigned long long)(unsigned int)lo);
}

// ---------------- 1. fused pooling partials (vision y<8, text y>=8) ----------------
__global__ __launch_bounds__(256) void pool_part_kernel(const float* __restrict__ v_pad,
                                                        const float* __restrict__ centers,
                                                        const int* __restrict__ grid_thws,
                                                        const float* __restrict__ t_pad,
                                                        const float* __restrict__ t_mask,
                                                        float* __restrict__ partV,
                                                        float* __restrict__ partT) {
    __shared__ float m_s[LCH * KV];   // 4 KB (text uses first TCH floats)
    const int b   = blockIdx.x;
    const int tid = threadIdx.x;

    if (blockIdx.y < LC) {
        // ---- vision chunk ----
        const int lc = blockIdx.y;
        const int H = grid_thws[1];
        const int W = grid_thws[2];
        int L = H * W; if (L > LMAX) L = LMAX;
        const int l0 = lc * LCH;

        for (int i = tid; i < LCH * KV; i += 256) {
            const int ll = i >> 3, k = i & 7;
            const int l  = l0 + ll;
            float m = 0.f;
            if (l < L) {
                const int iy = l / W, ix = l - iy * W;
                const float gx = (ix + 0.5f) / (float)W;
                const float gy = (iy + 0.5f) / (float)H;
                const float dx = centers[((size_t)b * KV + k) * 2 + 0] - gx;
                const float dy = centers[((size_t)b * KV + k) * 2 + 1] - gy;
                m = expf(-10.f * (dx * dx + dy * dy));
            }
            m_s[ll * KV + k] = m;
        }
        __syncthreads();
        if (tid < KV) {
            float s = 0.f;
            for (int ll = 0; ll < LCH; ++ll) s += m_s[ll * KV + tid];
            partV[PV_DEN + ((size_t)b * LC + lc) * KV + tid] = s;
        }

        const float* vp = v_pad + ((size_t)b * LMAX + l0) * DD + tid * 4;
        float4 acc[KV];
#pragma unroll
        for (int k = 0; k < KV; ++k) acc[k] = make_float4(0.f, 0.f, 0.f, 0.f);
#pragma unroll 4
        for (int ll = 0; ll < LCH; ++ll) {
            const float4 v = *(const float4*)(vp + (size_t)ll * DD);
#pragma unroll
            for (int k = 0; k < KV; ++k) {
                const float m = m_s[ll * KV + k];
                acc[k].x = fmaf(m, v.x, acc[k].x); acc[k].y = fmaf(m, v.y, acc[k].y);
                acc[k].z = fmaf(m, v.z, acc[k].z); acc[k].w = fmaf(m, v.w, acc[k].w);
            }
        }
#pragma unroll
        for (int k = 0; k < KV; ++k)
            *(float4*)(partV + PV_NUM + (((size_t)b * LC + lc) * KV + k) * DD + tid * 4) = acc[k];
    } else {
        // ---- text chunk ----
        const int tc = blockIdx.y - LC;
        const int t0 = tc * TCH;
        if (tid < TCH) m_s[tid] = t_mask[(size_t)b * TT + t0 + tid];
        __syncthreads();
        if (tid == 0) {
            float s = 0.f;
            for (int i = 0; i < TCH; ++i) s += m_s[i];
            partT[PT_DEN + (size_t)b * TC + tc] = s;
        }
        const float* tp = t_pad + ((size_t)b * TT + t0) * DD + tid * 4;
        float4 acc = make_float4(0.f, 0.f, 0.f, 0.f);
#pragma unroll 4
        for (int t = 0; t < TCH; ++t) {
            const float4 v = *(const float4*)(tp + (size_t)t * DD);
            const float m = m_s[t];
            acc.x = fmaf(m, v.x, acc.x); acc.y = fmaf(m, v.y, acc.y);
            acc.z = fmaf(m, v.z, acc.z); acc.w = fmaf(m, v.w, acc.w);
        }
        *(float4*)(partT + PT_NUM + ((size_t)b * TC + tc) * DD + tid * 4) = acc;
    }
}

// ---------------- 2. fused combine + normalize + hi-plane ----------------
__device__ inline void comb_norm_emit(float4 vv, int r, int tid,
                                      float* __restrict__ out_row,
                                      float* __restrict__ ws, size_t xn_off, size_t hi_off) {
    *(float4*)(out_row + tid * 4) = vv;
    float ss = vv.x * vv.x + vv.y * vv.y + vv.z * vv.z + vv.w * vv.w;
#pragma unroll
    for (int off = 32; off; off >>= 1) ss += __shfl_down(ss, off);
    __shared__ float wsum[4];
    if ((tid & 63) == 0) wsum[tid >> 6] = ss;
    __syncthreads();
    const float tot = wsum[0] + wsum[1] + wsum[2] + wsum[3];
    const float scale = 1.f / fmaxf(sqrtf(tot), 1e-12f);
    float4 xn;
    xn.x = vv.x * scale; xn.y = vv.y * scale; xn.z = vv.z * scale; xn.w = vv.w * scale;
    *(float4*)(ws + xn_off + (size_t)r * DD + tid * 4) = xn;
    const float f[4] = {xn.x, xn.y, xn.z, xn.w};
    s16x4 hv;
#pragma unroll
    for (int c = 0; c < 4; ++c) hv[c] = (short)f2bf_rn(f[c]);
    *(s16x4*)((short*)(ws + hi_off) + (size_t)r * DD + tid * 4) = hv;
}

__global__ __launch_bounds__(256) void pool_comb_kernel(const float* __restrict__ partV,
                                                        const float* __restrict__ partT,
                                                        float* __restrict__ out_views,
                                                        float* __restrict__ out_tg,
                                                        float* __restrict__ ws) {
    const int b   = blockIdx.x;
    const int k   = blockIdx.y;       // 0..7 vision view, 8 text
    const int tid = threadIdx.x;
    if (k < KV) {
        float den = 1e-6f;
        for (int lc = 0; lc < LC; ++lc) den += partV[PV_DEN + ((size_t)b * LC + lc) * KV + k];
        float4 s = make_float4(0.f, 0.f, 0.f, 0.f);
        for (int lc = 0; lc < LC; ++lc) {
            const float4 p = *(const float4*)(partV + PV_NUM + (((size_t)b * LC + lc) * KV + k) * DD + tid * 4);
            s.x += p.x; s.y += p.y; s.z += p.z; s.w += p.w;
        }
        const float inv = 1.f / den;
        float4 vv = make_float4(s.x * inv, s.y * inv, s.z * inv, s.w * inv);
        const int r = b * KV + k;
        comb_norm_emit(vv, r, tid, out_views + (size_t)r * DD, ws, WS_VN, WS_AHI_V);
    } else {
        float den = 1e-6f;
        for (int tc = 0; tc < TC; ++tc) den += partT[PT_DEN + (size_t)b * TC + tc];
        float4 s = make_float4(0.f, 0.f, 0.f, 0.f);
        for (int tc = 0; tc < TC; ++tc) {
            const float4 p = *(const float4*)(partT + PT_NUM + ((size_t)b * TC + tc) * DD + tid * 4);
            s.x += p.x; s.y += p.y; s.z += p.z; s.w += p.w;
        }
        const float inv = 1.f / den;
        float4 vv = make_float4(s.x * inv, s.y * inv, s.z * inv, s.w * inv);
        comb_norm_emit(vv, b, tid, out_tg + (size_t)b * DD, ws, WS_TN, WS_AHI_T);
    }
}

// ---------------- 4. 2-pass split-bf16 MFMA GEMM, register-prefetch pipelined ----------------
// computed = hi(x) . (hi(y)+lo(y)) = hi(x).y  (error sigma ~3.5e-5, absorbed by topk re-rank)
// K-loop: write_lds(tile k from regs) | barrier | issue loads(k+1)->regs | MFMA(k) | barrier
// so global-load latency hides under the MFMA phase instead of serializing with it.
constexpr int GBM = 128, GBN = 128, GBK = 64;

__device__ inline int fragoff(int sub, int g, int r16) {
    return (((sub * 8 + g) * 16) + (r16 ^ ((g & 7) << 1))) * 8;
}

__global__ __launch_bounds__(256) void gemm_acts_mfma(const float* __restrict__ encV,
                                                      const float* __restrict__ encT,
                                                      float* __restrict__ out,
                                                      float* __restrict__ ws) {
    __shared__ short Ah[GBM * GBK];                  // 16 KB
    __shared__ short Bh[GBN * GBK], Bl[GBN * GBK];   // 16 KB each
    __shared__ float bn_part[GBN][8];                // 4 KB
    __shared__ float binv_s[GBN];

    const int tid  = threadIdx.x;
    const int lane = tid & 63;
    const int wv   = tid >> 6;       // 0..3
    const int wm   = wv & 1;         // wave m-tile (64 rows)
    const int wn   = wv >> 1;        // wave n-tile (64 cols)
    // XCD-grouped mapping: consecutive blocks on one XCD share the enc h-tile
    const int bid  = blockIdx.x;
    const int xcd  = bid & 7;
    const int slot = bid >> 3;        // 0..79
    const int hb   = xcd + 8 * (slot / 5);   // 0..127
    const int my   = slot % 5;               // 0..3 vision m-tile, 4 text
    const bool isT = (my == 4);
    const int h0   = hb * GBN;
    const int m0   = isT ? 0 : my * GBM;
    const int M    = isT ? NROW_T : NROW_V;
    const float* Bm = isT ? encT : encV;
    const short* AhiP = (const short*)(ws + (isT ? WS_AHI_T : WS_AHI_V));
    float* outActs = out + (isT ? OUT_LAT_T : OUT_LAT_V);
    float* binv_g  = ws + (isT ? WS_BINV_T : WS_BINV_V);

    // per-thread staging task coordinates (fixed across K-steps)
    const int ksA = tid & 7;              // A: rt in 0..3 -> row lrA = (rt*256+tid)>>3
    const int ksB = tid & 7;              // B: same k-slot pattern
    int lrA[4], lrB[4];
#pragma unroll
    for (int rt = 0; rt < 4; ++rt) {
        lrA[rt] = (rt * 256 + tid) >> 3;              // 0..127
        lrB[rt] = (((rt + 4) * 256 + tid) >> 3) - GBM; // 0..127
    }

    f32x4 acc[4][4];
#pragma unroll
    for (int mi = 0; mi < 4; ++mi)
#pragma unroll
        for (int ni = 0; ni < 4; ++ni) acc[mi][ni] = (f32x4){0.f, 0.f, 0.f, 0.f};
    float bnacc[4] = {0.f, 0.f, 0.f, 0.f};

    // prefetch registers
    bf16x8 pa[4];
    float4 pb0[4], pb1[4];

    auto issue_loads = [&](int kt) {
#pragma unroll
        for (int rt = 0; rt < 4; ++rt) {
            if (m0 + lrA[rt] < M)
                pa[rt] = *(const bf16x8*)&AhiP[(size_t)(m0 + lrA[rt]) * DD + kt + ksA * 8];
            else
                pa[rt] = (bf16x8){0, 0, 0, 0, 0, 0, 0, 0};
        }
#pragma unroll
        for (int rt = 0; rt < 4; ++rt) {
            const float* src = Bm + (size_t)(h0 + lrB[rt]) * DD + kt + ksB * 8;
            pb0[rt] = *(const float4*)src;
            pb1[rt] = *(const float4*)(src + 4);
        }
    };

    auto write_lds = [&]() {
#pragma unroll
        for (int rt = 0; rt < 4; ++rt)
            *(bf16x8*)&Ah[fragoff(lrA[rt] >> 4, ksA, lrA[rt] & 15)] = pa[rt];
#pragma unroll
        for (int rt = 0; rt < 4; ++rt) {
            const float f[8] = {pb0[rt].x, pb0[rt].y, pb0[rt].z, pb0[rt].w,
                                pb1[rt].x, pb1[rt].y, pb1[rt].z, pb1[rt].w};
            bf16x8 hv, lv;
            float bsum = 0.f;
#pragma unroll
            for (int j = 0; j < 8; ++j) {
                const unsigned short hb16 = f2bf_rn(f[j]);
                const float hf = __uint_as_float((unsigned)hb16 << 16);
                hv[j] = (short)hb16;
                lv[j] = (short)f2bf_rn(f[j] - hf);
                bsum = fmaf(f[j], f[j], bsum);
            }
            bnacc[rt] += bsum;
            const int off = fragoff(lrB[rt] >> 4, ksB, lrB[rt] & 15);
            *(bf16x8*)&Bh[off] = hv; *(bf16x8*)&Bl[off] = lv;
        }
    };

    issue_loads(0);
    for (int kt = 0; kt < DD; kt += GBK) {
        write_lds();                       // consumes regs of tile kt
        __syncthreads();                   // publish LDS tile kt
        if (kt + GBK < DD) issue_loads(kt + GBK);   // prefetch k+1 (in flight during MFMA)

#pragma unroll
        for (int s = 0; s < 2; ++s) {      // two K=32 sub-steps per BK=64
            bf16x8 ah[4], bh[4], bl[4];
            const int g = s * 4 + (lane >> 4);
            const int r16 = lane & 15;
#pragma unroll
            for (int t = 0; t < 4; ++t) {
                ah[t] = *(const bf16x8*)&Ah[fragoff(wm * 4 + t, g, r16)];
                const int bo = fragoff(wn * 4 + t, g, r16);
                bh[t] = *(const bf16x8*)&Bh[bo];
                bl[t] = *(const bf16x8*)&Bl[bo];
            }
#pragma unroll
            for (int mi = 0; mi < 4; ++mi)
#pragma unroll
                for (int ni = 0; ni < 4; ++ni) {
                    acc[mi][ni] = __builtin_amdgcn_mfma_f32_16x16x32_bf16(ah[mi], bh[ni], acc[mi][ni], 0, 0, 0);
                    acc[mi][ni] = __builtin_amdgcn_mfma_f32_16x16x32_bf16(ah[mi], bl[ni], acc[mi][ni], 0, 0, 0);
                }
        }
        __syncthreads();                   // LDS free for next write_lds
    }

    // enc row norms from fused sumsq
#pragma unroll
    for (int rt = 0; rt < 4; ++rt)
        bn_part[lrB[rt]][ksB] = bnacc[rt];
    __syncthreads();
    if (tid < GBN) {
        float s = 0.f;
#pragma unroll
        for (int i = 0; i < 8; ++i) s += bn_part[tid][i];
        const float bi = 1.f / fmaxf(sqrtf(s), 1e-12f);
        binv_s[tid] = bi;
        if (my == 0 || my == 4) binv_g[h0 + tid] = bi;   // persist for topk's f64 re-rank
    }
    __syncthreads();

    // epilogue: scale by binv, clip, acts transform, store f32
#pragma unroll
    for (int mi = 0; mi < 4; ++mi)
#pragma unroll
        for (int ni = 0; ni < 4; ++ni) {
            const int hl = wn * 64 + ni * 16 + (lane & 15);
            const float bi = binv_s[hl];
#pragma unroll
            for (int j = 0; j < 4; ++j) {
                const int m = m0 + wm * 64 + mi * 16 + (lane >> 4) * 4 + j;
                if (m < M) {
                    float c = acc[mi][ni][j] * bi;
                    c = fminf(1.f, fmaxf(-1.f, c));
                    outActs[(size_t)m * HSAE + h0 + hl] = 2.f - sqrtf(fmaxf(0.f, 2.f - 2.f * c));
                }
            }
        }
}

// ---------------- 5. top-32: histogram screen (monotone-key margin) + f64 re-rank ----------------
constexpr int NBINS = 2048;
constexpr int NFINE = 256;
constexpr int CAP   = 512;
constexpr int BANDCAP = 128;
constexpr int MARGIN  = 12;        // fine bins: 12*1.22e-4 = 1.46e-3 >= 4*RANKEPS + bin
constexpr float RANKEPS = 2.5e-4f; // ~7 sigma of 2-pass GEMM acts error

__global__ __launch_bounds__(256) void topk_kernel(float* __restrict__ out_buf,
                                                   float* __restrict__ ws,
                                                   const float* __restrict__ enc_v,
                                                   const float* __restrict__ enc_t) {
    const int r    = blockIdx.x;
    const int tid  = threadIdx.x;
    const int wv   = tid >> 6;
    const int lane = tid & 63;
    float* row;
    int* idxp; float* valp;
    const float* xn; const float* enc; const float* binv;
    if (r < NROW_V) {
        row  = out_buf + OUT_LAT_V + (size_t)r * HSAE;
        idxp = (int*)(ws + WS_IDX_V) + (size_t)r * TOPK;
        valp = ws + WS_VAL_V + (size_t)r * TOPK;
        xn   = ws + WS_VN + (size_t)r * DD;
        enc  = enc_v; binv = ws + WS_BINV_V;
    } else {
        const int rr = r - NROW_V;
        row  = out_buf + OUT_LAT_T + (size_t)rr * HSAE;
        idxp = (int*)(ws + WS_IDX_T) + (size_t)rr * TOPK;
        valp = ws + WS_VAL_T + (size_t)rr * TOPK;
        xn   = ws + WS_TN + (size_t)rr * DD;
        enc  = enc_t; binv = ws + WS_BINV_T;
    }

    __shared__ unsigned int hist[4][NBINS];       // 32 KB
    __shared__ unsigned int fine[4][NFINE];       // 4 KB
    __shared__ float xs[DD];                      // 4 KB
    __shared__ unsigned long long cand[CAP];      // 4 KB
    __shared__ unsigned long long ord[CAP];       // 4 KB
    __shared__ double bval[BANDCAP];
    __shared__ int    bidx[BANDCAP];
    __shared__ int s_ncand, s_bin, s_cntgt, s_sub, s_A, s_E;

    for (int i = tid; i < 4 * NBINS; i += 256) ((unsigned int*)hist)[i] = 0u;
    for (int i = tid; i < 4 * NFINE; i += 256) ((unsigned int*)fine)[i] = 0u;
    if (tid == 0) { s_ncand = 0; }
    *(float4*)&xs[tid * 4] = *(const float4*)&xn[tid * 4];

    unsigned int bcache[64];
#pragma unroll
    for (int e = 0; e < 16; ++e) {
        const float4 v = *(const float4*)(row + (size_t)e * 1024 + tid * 4);
        bcache[e * 4 + 0] = __float_as_uint(v.x);
        bcache[e * 4 + 1] = __float_as_uint(v.y);
        bcache[e * 4 + 2] = __float_as_uint(v.z);
        bcache[e * 4 + 3] = __float_as_uint(v.w);
    }
#pragma unroll
    for (int e = 0; e < 16; ++e)
        *(float4*)(row + (size_t)e * 1024 + tid * 4) = make_float4(0.f, 0.f, 0.f, 0.f);
    __syncthreads();

    // ---- coarse histogram ----
#pragma unroll
    for (int e = 0; e < 64; ++e) {
        unsigned int bin = bcache[e] >> 19;
        if (bin > NBINS - 1) bin = NBINS - 1;
        atomicAdd(&hist[wv][bin], 1u);
    }
    __syncthreads();
    for (int i = tid; i < NBINS; i += 256)
        hist[0][i] += hist[1][i] + hist[2][i] + hist[3][i];
    __syncthreads();

    // ---- coarse boundary bin B0 + count strictly above ----
    if (tid < 64) {
        unsigned int csum = 0;
#pragma unroll
        for (int j = 0; j < 32; ++j)
            csum += hist[0][tid * 32 + ((tid + j) & 31)];
        unsigned int suf = csum;
#pragma unroll
        for (int off = 1; off < 64; off <<= 1) {
            unsigned int o = __shfl_down(suf, off);
            suf += (tid + off < 64) ? o : 0u;
        }
        if (suf >= (unsigned)TOPK && (suf - csum) < (unsigned)TOPK) {
            unsigned int run = suf - csum;
            int b = tid * 32 + 31;
            for (; b > tid * 32; --b) {
                const unsigned int h = hist[0][b];
                if (run + h >= (unsigned)TOPK) break;
                run += h;
            }
            s_bin = b; s_cntgt = (int)run;
        }
    }
    __syncthreads();
    const unsigned int B0 = (unsigned int)s_bin;
    const int r0 = TOPK - s_cntgt;         // local rank needed inside B0

    // ---- fine histogram over B0's elements ----
#pragma unroll
    for (int e = 0; e < 64; ++e) {
        const unsigned int bits = bcache[e];
        unsigned int bin = bits >> 19;
        if (bin > NBINS - 1) bin = NBINS - 1;
        if (bin == B0) atomicAdd(&fine[wv][(bits >> 11) & 255u], 1u);
    }
    __syncthreads();
    for (int i = tid; i < NFINE; i += 256)
        fine[0][i] += fine[1][i] + fine[2][i] + fine[3][i];
    __syncthreads();

    // ---- fine boundary sub-bin S0 (contains local rank r0) ----
    if (tid < 64) {
        unsigned int csum = fine[0][tid * 4] + fine[0][tid * 4 + 1] +
                            fine[0][tid * 4 + 2] + fine[0][tid * 4 + 3];
        unsigned int suf = csum;
#pragma unroll
        for (int off = 1; off < 64; off <<= 1) {
            unsigned int o = __shfl_down(suf, off);
            suf += (tid + off < 64) ? o : 0u;
        }
        if (suf >= (unsigned)r0 && (suf - csum) < (unsigned)r0) {
            unsigned int run = suf - csum;
            int b = tid * 4 + 3;
            for (; b > tid * 4; --b) {
                const unsigned int h = fine[0][b];
                if (run + h >= (unsigned)r0) break;
                run += h;
            }
            s_sub = b;
        }
    }
    __syncthreads();
    // monotone combined key threshold: boundary cf minus MARGIN fine bins
    const unsigned int cf0 = (B0 << 8) | (unsigned)s_sub;
    const unsigned int cfTh = cf0 - (unsigned)MARGIN;   // cf0 >> MARGIN always (acts ~0.6)

    // ---- compact candidates: (bits>>11) >= cfTh ----
#pragma unroll
    for (int e = 0; e < 64; ++e) {
        const unsigned int bits = bcache[e];
        if ((bits >> 11) >= cfTh) {
            const int slot = atomicAdd(&s_ncand, 1);
            if (slot < CAP) {
                const unsigned int idx = (unsigned)(e >> 2) * 1024u + (unsigned)tid * 4u + (unsigned)(e & 3);
                cand[slot] = ((unsigned long long)bits << 32) | (unsigned long long)(16383u - idx);
            }
        }
    }
    __syncthreads();
    const int nc = (s_ncand < CAP) ? s_ncand : CAP;

    // exact rank among candidates by GEMM value (unique keys) -> ordered list
    for (int i = tid; i < nc; i += 256) {
        const unsigned long long K = cand[i];
        int rank = 0;
        for (int j = 0; j < nc; ++j) rank += (cand[j] > K) ? 1 : 0;
        ord[rank] = K;
    }
    if (tid == 0) { s_A = nc; s_E = nc; }
    __syncthreads();

    const float Tv = __uint_as_float((unsigned)(ord[31] >> 32));  // 32nd GEMM value
    for (int i = tid; i < nc; i += 256) {
        const float v = __uint_as_float((unsigned)(ord[i] >> 32));
        if (v <= Tv + 2.f * RANKEPS) atomicMin(&s_A, i);   // first possibly-ambiguous
        if (v <  Tv - 2.f * RANKEPS) atomicMin(&s_E, i);   // first certainly-out
    }
    __syncthreads();
    const int A = s_A;                                 // ranks [0,A): certainly in
    int E = s_E; if (E > A + BANDCAP) E = A + BANDCAP; // band ranks [A,E)
    const int nb = E - A;

    // f64 recompute of the ambiguous band (typically ~4-8 elements)
    for (int t = A + wv; t < E; t += 4) {
        const int idx = 16383 - (int)(ord[t] & 0xffffffffull);
        const float* er = enc + (size_t)idx * DD;
        double s = 0.0;
#pragma unroll
        for (int i = 0; i < 16; ++i) {
            const int j = lane + i * 64;
            s = fma((double)xs[j], (double)er[j], s);
        }
#pragma unroll
        for (int off = 32; off; off >>= 1) s += shfl_down_dbl(s, off);
        if (lane == 0) {
            double c = s * (double)binv[idx];
            c = fmin(1.0, fmax(-1.0, c));
            bval[t - A] = 2.0 - sqrt(fmax(0.0, 2.0 - 2.0 * c));
            bidx[t - A] = idx;
        }
    }
    __syncthreads();

    // emit certain winners (ranks [0,A))
    for (int i = tid; i < A; i += 256) {
        const int idx  = 16383 - (int)(ord[i] & 0xffffffffull);
        const float v  = __uint_as_float((unsigned)(ord[i] >> 32));
        idxp[i] = idx; valp[i] = v; row[idx] = v;
    }
    // emit band winners by exact f64 order (slots [A,32))
    for (int t = tid; t < nb; t += 256) {
        int fr = 0;
        for (int u = 0; u < nb; ++u)
            if (bval[u] > bval[t] || (bval[u] == bval[t] && bidx[u] < bidx[t])) fr++;
        const int slot = A + fr;
        if (slot < TOPK) {
            const float v = (float)bval[t];
            idxp[slot] = bidx[t]; valp[slot] = v; row[bidx[t]] = v;
        }
    }
}

// ---------------- 6. fused sparse reconstruction (V blocks 0..1023, T 1024..2047) ----------------
__global__ __launch_bounds__(256) void recon_kernel(const float* __restrict__ dvw,
                                                    const float* __restrict__ dvb,
                                                    const float* __restrict__ dtw,
                                                    const float* __restrict__ dtb,
                                                    const float* __restrict__ ws,
                                                    float* __restrict__ out) {
    __shared__ float wrow[HSAE];  // 64 KB
    const int bid = blockIdx.x;
    const bool isT = bid >= DD;
    const int d   = isT ? bid - DD : bid;
    const int tid = threadIdx.x;
    const float* decw = isT ? dtw : dvw;
    const float* decb = isT ? dtb : dvb;
    const int*   idxp = (const int*)(ws + (isT ? WS_IDX_T : WS_IDX_V));
    const float* valp = ws + (isT ? WS_VAL_T : WS_VAL_V);
    float* outp = out + (isT ? OUT_RECON_T : OUT_RECON_V);
    const int M = isT ? NROW_T : NROW_V;

    const float* wr = decw + (size_t)d * HSAE;
    for (int e = 0; e < HSAE / (256 * 4); ++e)
        *(float4*)&wrow[(size_t)(e * 256 + tid) * 4] = *(const float4*)(wr + (size_t)(e * 256 + tid) * 4);
    __syncthreads();
    const float bias = decb[d];
    for (int n = tid; n < M; n += 256) {
        float acc = bias;
#pragma unroll
        for (int k = 0; k < TOPK; ++k)
            acc = fmaf(valp[n * TOPK + k], wrow[idxp[n * TOPK + k]], acc);
        outp[(size_t)n * DD + d] = acc;
    }
}

// ---------------- launch ----------------
extern "C" void kernel_launch(void* const* d_in, const int* in_sizes, int n_in,
                              void* d_out, int out_size, void* d_ws, size_t ws_size,
                              hipStream_t stream) {
    const float* v_pad    = (const float*)d_in[0];
    // d_in[1] v_len: unused by the reference
    const int*   grid_thws = (const int*)d_in[2];
    const float* t_pad    = (const float*)d_in[3];
    const float* t_mask   = (const float*)d_in[4];
    const float* centers  = (const float*)d_in[5];
    const float* enc_v    = (const float*)d_in[6];
    const float* dec_v_w  = (const float*)d_in[7];
    const float* dec_v_b  = (const float*)d_in[8];
    const float* enc_t    = (const float*)d_in[9];
    const float* dec_t_w  = (const float*)d_in[10];
    const float* dec_t_b  = (const float*)d_in[11];
    float* out = (float*)d_out;
    float* ws  = (float*)d_ws;

    pool_part_kernel<<<dim3(NB, LC + TC), 256, 0, stream>>>(v_pad, centers, grid_thws, t_pad, t_mask,
                                                            out + OUT_LAT_V, out + OUT_LAT_T);
    pool_comb_kernel<<<dim3(NB, KV + 1), 256, 0, stream>>>(out + OUT_LAT_V, out + OUT_LAT_T,
                                                           out + OUT_VVIEWS, out + OUT_TGLOBAL, ws);
    gemm_acts_mfma<<<640, 256, 0, stream>>>(enc_v, enc_t, out, ws);
    topk_kernel<<<NROW_V + NROW_T, 256, 0, stream>>>(out, ws, enc_v, enc_t);
    recon_kernel<<<2 * DD, 256, 0, stream>>>(dec_v_w, dec_v_b, dec_t_w, dec_t_b, ws, out);
}